// Round 3
// baseline (230.680 us; speedup 1.0000x reference)
//
#include <hip/hip_runtime.h>
#include <hip/hip_bf16.h>

#define NB 2
#define ND 1024
#define NL 4096
#define NFS 4
#define NDEPTH 11
#define LN_EPS 1e-5f

#define BM 128
#define BN 128
#define BK 32

#define CPAD 3072  // 3*max_dil zeros in front of the row

typedef __bf16 bf16x8 __attribute__((ext_vector_type(8)));
typedef float f32x4 __attribute__((ext_vector_type(4)));

__device__ __forceinline__ unsigned short f2bf(float f) {
    __hip_bfloat16 h = __float2bfloat16(f);
    unsigned short u;
    __builtin_memcpy(&u, &h, 2);
    return u;
}

__device__ __forceinline__ unsigned int pack2bf(float lo, float hi) {
    return (unsigned int)f2bf(lo) | ((unsigned int)f2bf(hi) << 16);
}

// async global->LDS, 16B per lane (wave-uniform LDS base + lane*16)
__device__ __forceinline__ void llds16(const void* g, void* l) {
    __builtin_amdgcn_global_load_lds(
        (const __attribute__((address_space(1))) unsigned int*)g,
        (__attribute__((address_space(3))) unsigned int*)l, 16, 0, 0);
}

// ---------------------------------------------------------------- K0: W -> bf16
__global__ __launch_bounds__(256) void wconv_kernel(const float* __restrict__ w,
                                                    unsigned short* __restrict__ wbf) {
    const int idx8 = (blockIdx.x * 256 + threadIdx.x) * 8;
    const float4 v0 = *reinterpret_cast<const float4*>(w + idx8);
    const float4 v1 = *reinterpret_cast<const float4*>(w + idx8 + 4);
    uint4 o;
    o.x = pack2bf(v0.x, v0.y);
    o.y = pack2bf(v0.z, v0.w);
    o.z = pack2bf(v1.x, v1.y);
    o.w = pack2bf(v1.z, v1.w);
    *reinterpret_cast<uint4*>(wbf + idx8) = o;
}

// ------------------------------------------------- K1: dilated conv cascade + gating
// one block per (b*ND + d) row; 256 threads, thread t owns positions i*256+t
// (strided: lane-stride-1 -> conflict-free LDS). Row lives in LDS behind a
// 3072-float zero pad so taps never need bounds checks; levels fully unrolled so
// every tap is ds_read_b32 with a compile-time immediate offset off base addr t.
__global__ __launch_bounds__(256) void conv_cascade_kernel(const float* __restrict__ x,
                                                           const float* __restrict__ h0,
                                                           const float* __restrict__ h1,
                                                           unsigned short* __restrict__ ybf) {
    __shared__ float a_sh[CPAD + NL];  // 28 KiB
    const int row = blockIdx.x;        // b*ND + d
    const int d = row & (ND - 1);
    const int t = threadIdx.x;

    // zero the pad once; never written again
#pragma unroll
    for (int i = 0; i < CPAD / 256; ++i) a_sh[i * 256 + t] = 0.f;

    const float* xrow = x + (size_t)row * NL;

    float h0c[NFS], h1c[NFS];
#pragma unroll
    for (int k = 0; k < NFS; ++k) {
        h0c[k] = h0[d * NFS + k];
        h1c[k] = h1[d * NFS + k];
    }

    float cur[16], yacc[16], bprev[16];
#pragma unroll
    for (int i = 0; i < 16; ++i) {
        cur[i] = xrow[i * 256 + t];
        a_sh[CPAD + i * 256 + t] = cur[i];
        yacc[i] = 0.f;
        bprev[i] = 0.f;
    }
    __syncthreads();

#pragma unroll
    for (int lev = 0; lev < NDEPTH; ++lev) {
        const int dil = 1 << lev;  // compile-time after unroll
        float anew[16], bnew[16];
#pragma unroll
        for (int i = 0; i < 16; ++i) {
            const int base = CPAD + i * 256 + t;  // folds to reg t + immediate
            const float a0 = cur[i];
            const float a1 = a_sh[base - dil];
            const float a2 = a_sh[base - 2 * dil];
            const float a3 = a_sh[base - 3 * dil];
            anew[i] = h0c[3] * a0 + h0c[2] * a1 + h0c[1] * a2 + h0c[0] * a3;
            bnew[i] = h1c[3] * a0 + h1c[2] * a1 + h1c[1] * a2 + h1c[0] * a3;
        }
        __syncthreads();  // all taps of this level consumed
#pragma unroll
        for (int i = 0; i < 16; ++i) a_sh[CPAD + i * 256 + t] = anew[i];

        if (lev >= 1) {
            // y += sigmoid(a_list[lev]) * b_list[lev-1]; lev==1 term counted twice
            const float sc = (lev == 1) ? 2.f : 1.f;
#pragma unroll
            for (int i = 0; i < 16; ++i) {
                const float sg = 1.f / (1.f + __expf(-anew[i]));
                yacc[i] += sc * sg * bprev[i];
            }
        }
#pragma unroll
        for (int i = 0; i < 16; ++i) {
            cur[i] = anew[i];
            bprev[i] = bnew[i];
        }
        __syncthreads();  // writes visible before next level's reads
        __builtin_amdgcn_sched_barrier(0);  // stop cross-level pipelining (R2 spill cause)
    }

#pragma unroll
    for (int i = 0; i < 16; ++i)
        ybf[(size_t)row * NL + i * 256 + t] = f2bf(yacc[i]);
}

// ------------------------------------------- K2: y [b][c][l] bf16 -> yT [b][l][c] bf16
__global__ __launch_bounds__(256) void transpose_kernel(const unsigned short* __restrict__ ybf,
                                                        unsigned short* __restrict__ yT) {
    __shared__ unsigned short tile[64][66];
    const int l0 = blockIdx.x * 64;
    const int c0 = blockIdx.y * 64;
    const int b = blockIdx.z;
    const int t = threadIdx.x;
    const int li = t & 63, cg = t >> 6;
#pragma unroll
    for (int k = 0; k < 16; ++k) {
        const int ci = cg * 16 + k;
        tile[ci][li] = ybf[(size_t)(b * ND + c0 + ci) * NL + l0 + li];
    }
    __syncthreads();
    const int ci2 = t & 63, lg = t >> 6;
#pragma unroll
    for (int k = 0; k < 16; ++k) {
        const int li2 = lg * 16 + k;
        yT[((size_t)b * NL + l0 + li2) * ND + c0 + ci2] = tile[ci2][li2];
    }
}

// --------------------------- K3: z[b][o][l] = (W @ y)[o][l] + b_mix[o] + x[b][o][l]
// bf16 MFMA 16x16x32; staging via global_load_lds width-16 (m97 pattern)
__global__ __launch_bounds__(256) void gemm_kernel(const unsigned short* __restrict__ wbf,
                                                   const unsigned short* __restrict__ yT,
                                                   const float* __restrict__ x,
                                                   const float* __restrict__ bmix,
                                                   float* __restrict__ z) {
    __shared__ unsigned short As[BM][BK];  // 8 KiB, linear [row][k]
    __shared__ unsigned short Bs[BN][BK];  // 8 KiB, linear [n][k]

    const int n0 = blockIdx.x * BN;
    const int m0 = blockIdx.y * BM;
    const int b = blockIdx.z;
    const int t = threadIdx.x;
    const int lane = t & 63, wid = t >> 6;
    const int wr = wid >> 1, wc = wid & 1;  // 2x2 waves, each 64x64
    const int fr = lane & 15;
    const int fk = (lane >> 4) * 8;

    const int srow = wid * 32 + (lane >> 2);
    const int sk = (lane & 3) * 8;
    const unsigned short* Ag = wbf + (size_t)(m0 + srow) * ND + sk;
    const unsigned short* Bg = yT + ((size_t)b * NL + n0 + srow) * ND + sk;
    unsigned short* AsD0 = &As[wid * 32][0];
    unsigned short* AsD1 = &As[wid * 32 + 16][0];
    unsigned short* BsD0 = &Bs[wid * 32][0];
    unsigned short* BsD1 = &Bs[wid * 32 + 16][0];

    f32x4 acc[4][4];
#pragma unroll
    for (int mi = 0; mi < 4; ++mi)
#pragma unroll
        for (int ni = 0; ni < 4; ++ni)
            acc[mi][ni] = (f32x4){0.f, 0.f, 0.f, 0.f};

    for (int kt = 0; kt < ND; kt += BK) {
        llds16(Ag + kt, AsD0);
        llds16(Ag + kt + 16 * ND, AsD1);
        llds16(Bg + kt, BsD0);
        llds16(Bg + kt + 16 * ND, BsD1);
        __syncthreads();

        bf16x8 af[4], bv[4];
#pragma unroll
        for (int mi = 0; mi < 4; ++mi)
            af[mi] = *reinterpret_cast<const bf16x8*>(&As[wr * 64 + mi * 16 + fr][fk]);
#pragma unroll
        for (int ni = 0; ni < 4; ++ni)
            bv[ni] = *reinterpret_cast<const bf16x8*>(&Bs[wc * 64 + ni * 16 + fr][fk]);
#pragma unroll
        for (int mi = 0; mi < 4; ++mi)
#pragma unroll
            for (int ni = 0; ni < 4; ++ni)
                acc[mi][ni] = __builtin_amdgcn_mfma_f32_16x16x32_bf16(af[mi], bv[ni],
                                                                      acc[mi][ni], 0, 0, 0);
        __syncthreads();
    }

    // epilogue: D[row][col], col = lane&15, row = (lane>>4)*4 + r
    const size_t bbase = (size_t)b * ND * NL;
#pragma unroll
    for (int mi = 0; mi < 4; ++mi) {
#pragma unroll
        for (int r = 0; r < 4; ++r) {
            const int o = m0 + wr * 64 + mi * 16 + (lane >> 4) * 4 + r;
            const float bm = bmix[o];
            const size_t rowbase = bbase + (size_t)o * NL;
#pragma unroll
            for (int ni = 0; ni < 4; ++ni) {
                const int l = n0 + wc * 64 + ni * 16 + fr;
                z[rowbase + l] = acc[mi][ni][r] + bm + x[rowbase + l];
            }
        }
    }
}

// ---------------------------------------------------- K4: LayerNorm over channels
__global__ __launch_bounds__(512) void ln_kernel(const float* __restrict__ z,
                                                 const float* __restrict__ gamma,
                                                 const float* __restrict__ beta,
                                                 float* __restrict__ out) {
    const int b = blockIdx.y;
    const int l0 = blockIdx.x * 32;
    const int tl = threadIdx.x & 31, tg = threadIdx.x >> 5;
    const float* zb = z + (size_t)b * ND * NL;
    float s = 0.f, q = 0.f;
    for (int c = tg; c < ND; c += 16) {
        const float v = zb[(size_t)c * NL + l0 + tl];
        s += v;
        q += v * v;
    }
    __shared__ float sred[16][33], qred[16][33];
    __shared__ float mu_s[32], rs_s[32];
    sred[tg][tl] = s;
    qred[tg][tl] = q;
    __syncthreads();
    if (tg == 0) {
        float S = 0.f, Q = 0.f;
#pragma unroll
        for (int g = 0; g < 16; ++g) {
            S += sred[g][tl];
            Q += qred[g][tl];
        }
        const float mu = S * (1.f / ND);
        const float var = Q * (1.f / ND) - mu * mu;
        mu_s[tl] = mu;
        rs_s[tl] = rsqrtf(var + LN_EPS);
    }
    __syncthreads();
    const float mu = mu_s[tl], rs = rs_s[tl];
    float* ob = out + (size_t)b * ND * NL;
    for (int c = tg; c < ND; c += 16) {
        const size_t idx = (size_t)c * NL + l0 + tl;
        const float v = zb[idx];
        ob[idx] = (v - mu) * rs * gamma[c] + beta[c];
    }
}

extern "C" void kernel_launch(void* const* d_in, const int* in_sizes, int n_in,
                              void* d_out, int out_size, void* d_ws, size_t ws_size,
                              hipStream_t stream) {
    (void)in_sizes; (void)n_in; (void)out_size; (void)ws_size;
    const float* x = (const float*)d_in[0];
    const float* h0 = (const float*)d_in[1];
    const float* h1 = (const float*)d_in[2];
    const float* wmix = (const float*)d_in[3];
    const float* bmix = (const float*)d_in[4];
    const float* gamma = (const float*)d_in[5];
    const float* beta = (const float*)d_in[6];
    float* out = (float*)d_out;

    char* ws = (char*)d_ws;
    unsigned short* ybf = (unsigned short*)(ws);                              // 16 MiB
    unsigned short* yT = (unsigned short*)(ws + (size_t)16 * 1024 * 1024);    // 16 MiB
    unsigned short* wbf = (unsigned short*)(ws + (size_t)32 * 1024 * 1024);   // 2 MiB
    float* z = (float*)(ws + (size_t)34 * 1024 * 1024);                       // 32 MiB

    wconv_kernel<<<dim3(ND * ND / (256 * 8)), 256, 0, stream>>>(wmix, wbf);
    conv_cascade_kernel<<<dim3(NB * ND), 256, 0, stream>>>(x, h0, h1, ybf);
    transpose_kernel<<<dim3(NL / 64, ND / 64, NB), 256, 0, stream>>>(ybf, yT);
    gemm_kernel<<<dim3(NL / BN, ND / BM, NB), 256, 0, stream>>>(wbf, yT, x, bmix, z);
    ln_kernel<<<dim3(NL / 32, NB), 512, 0, stream>>>(z, gamma, beta, out);
}

// Round 4
// 138.995 us; speedup vs baseline: 1.6596x; 1.6596x over previous
//
#include <hip/hip_runtime.h>
#include <hip/hip_bf16.h>

#define NB 2
#define ND 1024
#define NL 4096
#define NFS 4
#define NDEPTH 11
#define LN_EPS 1e-5f

#define BM 128
#define BN 128
#define BK 32

#define CPAD 3072  // 3*max_dil zeros in front of the row

typedef __bf16 bf16x8 __attribute__((ext_vector_type(8)));
typedef float f32x4 __attribute__((ext_vector_type(4)));

__device__ __forceinline__ unsigned short f2bf(float f) {
    __hip_bfloat16 h = __float2bfloat16(f);
    unsigned short u;
    __builtin_memcpy(&u, &h, 2);
    return u;
}

__device__ __forceinline__ unsigned int pack2bf(float lo, float hi) {
    return (unsigned int)f2bf(lo) | ((unsigned int)f2bf(hi) << 16);
}

// async global->LDS, 16B per lane (wave-uniform LDS base + lane*16)
__device__ __forceinline__ void llds16(const void* g, void* l) {
    __builtin_amdgcn_global_load_lds(
        (const __attribute__((address_space(1))) unsigned int*)g,
        (__attribute__((address_space(3))) unsigned int*)l, 16, 0, 0);
}

// ---------------------------------------------------------------- K0: W -> bf16
__global__ __launch_bounds__(256) void wconv_kernel(const float* __restrict__ w,
                                                    unsigned short* __restrict__ wbf) {
    const int idx8 = (blockIdx.x * 256 + threadIdx.x) * 8;
    const float4 v0 = *reinterpret_cast<const float4*>(w + idx8);
    const float4 v1 = *reinterpret_cast<const float4*>(w + idx8 + 4);
    uint4 o;
    o.x = pack2bf(v0.x, v0.y);
    o.y = pack2bf(v0.z, v0.w);
    o.z = pack2bf(v1.x, v1.y);
    o.w = pack2bf(v1.z, v1.w);
    *reinterpret_cast<uint4*>(wbf + idx8) = o;
}

// ------------------------------------------------- K1: dilated conv cascade + gating
// one block per (b*ND + d) row; 256 threads, thread t owns positions i*256+t
// (strided -> conflict-free LDS, bounded live ranges). Runtime level loop (R1's
// 64-VGPR structure); zero pad removes bounds checks; per-level hoisted tap base
// indices make every tap a ds_read_b32 with an immediate offset (i*1024 bytes).
__global__ __launch_bounds__(256) void conv_cascade_kernel(const float* __restrict__ x,
                                                           const float* __restrict__ h0,
                                                           const float* __restrict__ h1,
                                                           unsigned short* __restrict__ ybf) {
    __shared__ float a_sh[CPAD + NL];  // 28 KiB
    const int row = blockIdx.x;        // b*ND + d
    const int d = row & (ND - 1);
    const int t = threadIdx.x;

    // zero the pad once; never written again
#pragma unroll
    for (int i = 0; i < CPAD / 256; ++i) a_sh[i * 256 + t] = 0.f;

    const float* xrow = x + (size_t)row * NL;

    float h0c[NFS], h1c[NFS];
#pragma unroll
    for (int k = 0; k < NFS; ++k) {
        h0c[k] = h0[d * NFS + k];
        h1c[k] = h1[d * NFS + k];
    }

    float cur[16], yacc[16], bprev[16];
#pragma unroll
    for (int i = 0; i < 16; ++i) {
        cur[i] = xrow[i * 256 + t];
        a_sh[CPAD + i * 256 + t] = cur[i];
        yacc[i] = 0.f;
        bprev[i] = 0.f;
    }
    __syncthreads();

    int dil = 1;
#pragma unroll 1
    for (int lev = 0; lev < NDEPTH; ++lev) {
        // hoisted tap bases: one VGPR each, taps below use immediate offsets
        const int off1 = CPAD + t - dil;
        const int off2 = CPAD + t - 2 * dil;
        const int off3 = CPAD + t - 3 * dil;
        float anew[16], bnew[16];
#pragma unroll
        for (int i = 0; i < 16; ++i) {
            const float a0 = cur[i];
            const float a1 = a_sh[off1 + i * 256];
            const float a2 = a_sh[off2 + i * 256];
            const float a3 = a_sh[off3 + i * 256];
            anew[i] = h0c[3] * a0 + h0c[2] * a1 + h0c[1] * a2 + h0c[0] * a3;
            bnew[i] = h1c[3] * a0 + h1c[2] * a1 + h1c[1] * a2 + h1c[0] * a3;
        }
        __syncthreads();  // all taps of this level consumed
#pragma unroll
        for (int i = 0; i < 16; ++i) a_sh[CPAD + i * 256 + t] = anew[i];

        if (lev >= 1) {
            // y += sigmoid(a_list[lev]) * b_list[lev-1]; lev==1 term counted twice
            const float sc = (lev == 1) ? 2.f : 1.f;
#pragma unroll
            for (int i = 0; i < 16; ++i) {
                const float sg = 1.f / (1.f + __expf(-anew[i]));
                yacc[i] += sc * sg * bprev[i];
            }
        }
#pragma unroll
        for (int i = 0; i < 16; ++i) {
            cur[i] = anew[i];
            bprev[i] = bnew[i];
        }
        dil <<= 1;
        __syncthreads();  // writes visible before next level's reads
    }

#pragma unroll
    for (int i = 0; i < 16; ++i)
        ybf[(size_t)row * NL + i * 256 + t] = f2bf(yacc[i]);
}

// ------------------------------------------- K2: y [b][c][l] bf16 -> yT [b][l][c] bf16
__global__ __launch_bounds__(256) void transpose_kernel(const unsigned short* __restrict__ ybf,
                                                        unsigned short* __restrict__ yT) {
    __shared__ unsigned short tile[64][66];
    const int l0 = blockIdx.x * 64;
    const int c0 = blockIdx.y * 64;
    const int b = blockIdx.z;
    const int t = threadIdx.x;
    const int li = t & 63, cg = t >> 6;
#pragma unroll
    for (int k = 0; k < 16; ++k) {
        const int ci = cg * 16 + k;
        tile[ci][li] = ybf[(size_t)(b * ND + c0 + ci) * NL + l0 + li];
    }
    __syncthreads();
    const int ci2 = t & 63, lg = t >> 6;
#pragma unroll
    for (int k = 0; k < 16; ++k) {
        const int li2 = lg * 16 + k;
        yT[((size_t)b * NL + l0 + li2) * ND + c0 + ci2] = tile[ci2][li2];
    }
}

// --------------------------- K3: z[b][o][l] = (W @ y)[o][l] + b_mix[o] + x[b][o][l]
// bf16 MFMA 16x16x32; staging via global_load_lds width-16 (m97 pattern)
__global__ __launch_bounds__(256) void gemm_kernel(const unsigned short* __restrict__ wbf,
                                                   const unsigned short* __restrict__ yT,
                                                   const float* __restrict__ x,
                                                   const float* __restrict__ bmix,
                                                   float* __restrict__ z) {
    __shared__ unsigned short As[BM][BK];  // 8 KiB, linear [row][k]
    __shared__ unsigned short Bs[BN][BK];  // 8 KiB, linear [n][k]

    const int n0 = blockIdx.x * BN;
    const int m0 = blockIdx.y * BM;
    const int b = blockIdx.z;
    const int t = threadIdx.x;
    const int lane = t & 63, wid = t >> 6;
    const int wr = wid >> 1, wc = wid & 1;  // 2x2 waves, each 64x64
    const int fr = lane & 15;
    const int fk = (lane >> 4) * 8;

    const int srow = wid * 32 + (lane >> 2);
    const int sk = (lane & 3) * 8;
    const unsigned short* Ag = wbf + (size_t)(m0 + srow) * ND + sk;
    const unsigned short* Bg = yT + ((size_t)b * NL + n0 + srow) * ND + sk;
    unsigned short* AsD0 = &As[wid * 32][0];
    unsigned short* AsD1 = &As[wid * 32 + 16][0];
    unsigned short* BsD0 = &Bs[wid * 32][0];
    unsigned short* BsD1 = &Bs[wid * 32 + 16][0];

    f32x4 acc[4][4];
#pragma unroll
    for (int mi = 0; mi < 4; ++mi)
#pragma unroll
        for (int ni = 0; ni < 4; ++ni)
            acc[mi][ni] = (f32x4){0.f, 0.f, 0.f, 0.f};

    for (int kt = 0; kt < ND; kt += BK) {
        llds16(Ag + kt, AsD0);
        llds16(Ag + kt + 16 * ND, AsD1);
        llds16(Bg + kt, BsD0);
        llds16(Bg + kt + 16 * ND, BsD1);
        __syncthreads();

        bf16x8 af[4], bv[4];
#pragma unroll
        for (int mi = 0; mi < 4; ++mi)
            af[mi] = *reinterpret_cast<const bf16x8*>(&As[wr * 64 + mi * 16 + fr][fk]);
#pragma unroll
        for (int ni = 0; ni < 4; ++ni)
            bv[ni] = *reinterpret_cast<const bf16x8*>(&Bs[wc * 64 + ni * 16 + fr][fk]);
#pragma unroll
        for (int mi = 0; mi < 4; ++mi)
#pragma unroll
            for (int ni = 0; ni < 4; ++ni)
                acc[mi][ni] = __builtin_amdgcn_mfma_f32_16x16x32_bf16(af[mi], bv[ni],
                                                                      acc[mi][ni], 0, 0, 0);
        __syncthreads();
    }

    // epilogue: D[row][col], col = lane&15, row = (lane>>4)*4 + r
    const size_t bbase = (size_t)b * ND * NL;
#pragma unroll
    for (int mi = 0; mi < 4; ++mi) {
#pragma unroll
        for (int r = 0; r < 4; ++r) {
            const int o = m0 + wr * 64 + mi * 16 + (lane >> 4) * 4 + r;
            const float bm = bmix[o];
            const size_t rowbase = bbase + (size_t)o * NL;
#pragma unroll
            for (int ni = 0; ni < 4; ++ni) {
                const int l = n0 + wc * 64 + ni * 16 + fr;
                z[rowbase + l] = acc[mi][ni][r] + bm + x[rowbase + l];
            }
        }
    }
}

// ---------------------------------------------------- K4: LayerNorm over channels
__global__ __launch_bounds__(512) void ln_kernel(const float* __restrict__ z,
                                                 const float* __restrict__ gamma,
                                                 const float* __restrict__ beta,
                                                 float* __restrict__ out) {
    const int b = blockIdx.y;
    const int l0 = blockIdx.x * 32;
    const int tl = threadIdx.x & 31, tg = threadIdx.x >> 5;
    const float* zb = z + (size_t)b * ND * NL;
    float s = 0.f, q = 0.f;
    for (int c = tg; c < ND; c += 16) {
        const float v = zb[(size_t)c * NL + l0 + tl];
        s += v;
        q += v * v;
    }
    __shared__ float sred[16][33], qred[16][33];
    __shared__ float mu_s[32], rs_s[32];
    sred[tg][tl] = s;
    qred[tg][tl] = q;
    __syncthreads();
    if (tg == 0) {
        float S = 0.f, Q = 0.f;
#pragma unroll
        for (int g = 0; g < 16; ++g) {
            S += sred[g][tl];
            Q += qred[g][tl];
        }
        const float mu = S * (1.f / ND);
        const float var = Q * (1.f / ND) - mu * mu;
        mu_s[tl] = mu;
        rs_s[tl] = rsqrtf(var + LN_EPS);
    }
    __syncthreads();
    const float mu = mu_s[tl], rs = rs_s[tl];
    float* ob = out + (size_t)b * ND * NL;
    for (int c = tg; c < ND; c += 16) {
        const size_t idx = (size_t)c * NL + l0 + tl;
        const float v = zb[idx];
        ob[idx] = (v - mu) * rs * gamma[c] + beta[c];
    }
}

extern "C" void kernel_launch(void* const* d_in, const int* in_sizes, int n_in,
                              void* d_out, int out_size, void* d_ws, size_t ws_size,
                              hipStream_t stream) {
    (void)in_sizes; (void)n_in; (void)out_size; (void)ws_size;
    const float* x = (const float*)d_in[0];
    const float* h0 = (const float*)d_in[1];
    const float* h1 = (const float*)d_in[2];
    const float* wmix = (const float*)d_in[3];
    const float* bmix = (const float*)d_in[4];
    const float* gamma = (const float*)d_in[5];
    const float* beta = (const float*)d_in[6];
    float* out = (float*)d_out;

    char* ws = (char*)d_ws;
    unsigned short* ybf = (unsigned short*)(ws);                              // 16 MiB
    unsigned short* yT = (unsigned short*)(ws + (size_t)16 * 1024 * 1024);    // 16 MiB
    unsigned short* wbf = (unsigned short*)(ws + (size_t)32 * 1024 * 1024);   // 2 MiB
    float* z = (float*)(ws + (size_t)34 * 1024 * 1024);                       // 32 MiB

    wconv_kernel<<<dim3(ND * ND / (256 * 8)), 256, 0, stream>>>(wmix, wbf);
    conv_cascade_kernel<<<dim3(NB * ND), 256, 0, stream>>>(x, h0, h1, ybf);
    transpose_kernel<<<dim3(NL / 64, ND / 64, NB), 256, 0, stream>>>(ybf, yT);
    gemm_kernel<<<dim3(NL / BN, ND / BM, NB), 256, 0, stream>>>(wbf, yT, x, bmix, z);
    ln_kernel<<<dim3(NL / 32, NB), 512, 0, stream>>>(z, gamma, beta, out);
}

// Round 5
// 108.832 us; speedup vs baseline: 2.1196x; 1.2771x over previous
//
#include <hip/hip_runtime.h>
#include <hip/hip_bf16.h>

#define NB 2
#define ND 1024
#define NL 4096
#define NFS 4
#define NDEPTH 11
#define LN_EPS 1e-5f

#define BM 128
#define BN 128
#define BK 32

#define CPAD 384  // 3*dil at last LDS level (lev 7, dil=128)

typedef __bf16 bf16x8 __attribute__((ext_vector_type(8)));
typedef float f32x4 __attribute__((ext_vector_type(4)));

__device__ __forceinline__ unsigned short f2bf(float f) {
    __hip_bfloat16 h = __float2bfloat16(f);
    unsigned short u;
    __builtin_memcpy(&u, &h, 2);
    return u;
}

__device__ __forceinline__ float bf2f(unsigned short u) {
    unsigned int ui = (unsigned int)u << 16;
    float f;
    __builtin_memcpy(&f, &ui, 4);
    return f;
}

__device__ __forceinline__ unsigned int pack2bf(float lo, float hi) {
    return (unsigned int)f2bf(lo) | ((unsigned int)f2bf(hi) << 16);
}

// fast sigmoid: v_exp + raw v_rcp (avoids IEEE div_scale/div_fmas/div_fixup)
__device__ __forceinline__ float sigm(float v) {
    return __builtin_amdgcn_rcpf(1.f + __expf(-v));
}

// async global->LDS, 16B per lane (wave-uniform LDS base + lane*16)
__device__ __forceinline__ void llds16(const void* g, void* l) {
    __builtin_amdgcn_global_load_lds(
        (const __attribute__((address_space(1))) unsigned int*)g,
        (__attribute__((address_space(3))) unsigned int*)l, 16, 0, 0);
}

// ---------------------------------------------------------------- K0: W -> bf16
__global__ __launch_bounds__(256) void wconv_kernel(const float* __restrict__ w,
                                                    unsigned short* __restrict__ wbf) {
    const int idx8 = (blockIdx.x * 256 + threadIdx.x) * 8;
    const float4 v0 = *reinterpret_cast<const float4*>(w + idx8);
    const float4 v1 = *reinterpret_cast<const float4*>(w + idx8 + 4);
    uint4 o;
    o.x = pack2bf(v0.x, v0.y);
    o.y = pack2bf(v0.z, v0.w);
    o.z = pack2bf(v1.x, v1.y);
    o.w = pack2bf(v1.z, v1.w);
    *reinterpret_cast<uint4*>(wbf + idx8) = o;
}

// ------------------------------------------------- K1: dilated conv cascade + gating
// one block per (b*ND + d) row; 256 threads, thread t owns positions i*256+t.
// Levels 0..7 (dil<=128) read taps from LDS (runtime loop for 0..6, lev 7 skips the
// write-back). Levels 8..10 (dil = 256/512/1024 = multiples of the ownership stride)
// read taps from the thread's own cur[] registers: no LDS, no barriers.
__global__ __launch_bounds__(256) void conv_cascade_kernel(const float* __restrict__ x,
                                                           const float* __restrict__ h0,
                                                           const float* __restrict__ h1,
                                                           unsigned short* __restrict__ ybf) {
    __shared__ float a_sh[CPAD + NL];  // 17.9 KiB
    const int row = blockIdx.x;        // b*ND + d
    const int d = row & (ND - 1);
    const int t = threadIdx.x;

    // zero the 384-float pad
    if (t < CPAD - 256) a_sh[t] = 0.f;
    a_sh[(CPAD - 256) + t] = 0.f;

    const float* xrow = x + (size_t)row * NL;

    float h0c[NFS], h1c[NFS];
#pragma unroll
    for (int k = 0; k < NFS; ++k) {
        h0c[k] = h0[d * NFS + k];
        h1c[k] = h1[d * NFS + k];
    }

    float cur[16], yacc[16], bprev[16];
#pragma unroll
    for (int i = 0; i < 16; ++i) {
        cur[i] = xrow[i * 256 + t];
        a_sh[CPAD + i * 256 + t] = cur[i];
        yacc[i] = 0.f;
        bprev[i] = 0.f;
    }
    __syncthreads();

    int dil = 1;
#pragma unroll 1
    for (int lev = 0; lev < 7; ++lev) {
        const int off1 = CPAD + t - dil;
        const int off2 = CPAD + t - 2 * dil;
        const int off3 = CPAD + t - 3 * dil;
        float anew[16], bnew[16];
#pragma unroll
        for (int i = 0; i < 16; ++i) {
            const float a0 = cur[i];
            const float a1 = a_sh[off1 + i * 256];
            const float a2 = a_sh[off2 + i * 256];
            const float a3 = a_sh[off3 + i * 256];
            anew[i] = h0c[3] * a0 + h0c[2] * a1 + h0c[1] * a2 + h0c[0] * a3;
            bnew[i] = h1c[3] * a0 + h1c[2] * a1 + h1c[1] * a2 + h1c[0] * a3;
        }
        __syncthreads();  // all taps of this level consumed
#pragma unroll
        for (int i = 0; i < 16; ++i) a_sh[CPAD + i * 256 + t] = anew[i];

        if (lev >= 1) {
            const float sc = (lev == 1) ? 2.f : 1.f;
#pragma unroll
            for (int i = 0; i < 16; ++i)
                yacc[i] += sc * sigm(anew[i]) * bprev[i];
        }
#pragma unroll
        for (int i = 0; i < 16; ++i) {
            cur[i] = anew[i];
            bprev[i] = bnew[i];
        }
        dil <<= 1;
        __syncthreads();  // writes visible before next level's reads
    }

    // lev 7 (dil=128): LDS taps, no write-back (lev 8+ uses registers only)
    {
        const int off1 = CPAD + t - 128;
        const int off2 = CPAD + t - 256;
        const int off3 = CPAD + t - 384;
        float anew[16], bnew[16];
#pragma unroll
        for (int i = 0; i < 16; ++i) {
            const float a0 = cur[i];
            const float a1 = a_sh[off1 + i * 256];
            const float a2 = a_sh[off2 + i * 256];
            const float a3 = a_sh[off3 + i * 256];
            anew[i] = h0c[3] * a0 + h0c[2] * a1 + h0c[1] * a2 + h0c[0] * a3;
            bnew[i] = h1c[3] * a0 + h1c[2] * a1 + h1c[1] * a2 + h1c[0] * a3;
        }
#pragma unroll
        for (int i = 0; i < 16; ++i) {
            yacc[i] += sigm(anew[i]) * bprev[i];
            cur[i] = anew[i];
            bprev[i] = bnew[i];
        }
    }

    // lev 8 (dil=256): taps = cur[i-1..i-3]
    {
        float anew[16], bnew[16];
#pragma unroll
        for (int i = 0; i < 16; ++i) {
            const float a0 = cur[i];
            const float a1 = (i >= 1) ? cur[i - 1] : 0.f;
            const float a2 = (i >= 2) ? cur[i - 2] : 0.f;
            const float a3 = (i >= 3) ? cur[i - 3] : 0.f;
            anew[i] = h0c[3] * a0 + h0c[2] * a1 + h0c[1] * a2 + h0c[0] * a3;
            bnew[i] = h1c[3] * a0 + h1c[2] * a1 + h1c[1] * a2 + h1c[0] * a3;
        }
#pragma unroll
        for (int i = 0; i < 16; ++i) {
            yacc[i] += sigm(anew[i]) * bprev[i];
            cur[i] = anew[i];
            bprev[i] = bnew[i];
        }
    }

    // lev 9 (dil=512): taps = cur[i-2], cur[i-4], cur[i-6]
    {
        float anew[16], bnew[16];
#pragma unroll
        for (int i = 0; i < 16; ++i) {
            const float a0 = cur[i];
            const float a1 = (i >= 2) ? cur[i - 2] : 0.f;
            const float a2 = (i >= 4) ? cur[i - 4] : 0.f;
            const float a3 = (i >= 6) ? cur[i - 6] : 0.f;
            anew[i] = h0c[3] * a0 + h0c[2] * a1 + h0c[1] * a2 + h0c[0] * a3;
            bnew[i] = h1c[3] * a0 + h1c[2] * a1 + h1c[1] * a2 + h1c[0] * a3;
        }
#pragma unroll
        for (int i = 0; i < 16; ++i) {
            yacc[i] += sigm(anew[i]) * bprev[i];
            cur[i] = anew[i];
            bprev[i] = bnew[i];
        }
    }

    // lev 10 (dil=1024): taps = cur[i-4], cur[i-8], cur[i-12]; b-conv dead (unused)
#pragma unroll
    for (int i = 0; i < 16; ++i) {
        const float a0 = cur[i];
        const float a1 = (i >= 4) ? cur[i - 4] : 0.f;
        const float a2 = (i >= 8) ? cur[i - 8] : 0.f;
        const float a3 = (i >= 12) ? cur[i - 12] : 0.f;
        const float an = h0c[3] * a0 + h0c[2] * a1 + h0c[1] * a2 + h0c[0] * a3;
        yacc[i] += sigm(an) * bprev[i];
    }

#pragma unroll
    for (int i = 0; i < 16; ++i)
        ybf[(size_t)row * NL + i * 256 + t] = f2bf(yacc[i]);
}

// ------------------------------------------- K2: y [b][c][l] bf16 -> yT [b][l][c] bf16
__global__ __launch_bounds__(256) void transpose_kernel(const unsigned short* __restrict__ ybf,
                                                        unsigned short* __restrict__ yT) {
    __shared__ unsigned short tile[64][66];
    const int l0 = blockIdx.x * 64;
    const int c0 = blockIdx.y * 64;
    const int b = blockIdx.z;
    const int t = threadIdx.x;
    const int li = t & 63, cg = t >> 6;
#pragma unroll
    for (int k = 0; k < 16; ++k) {
        const int ci = cg * 16 + k;
        tile[ci][li] = ybf[(size_t)(b * ND + c0 + ci) * NL + l0 + li];
    }
    __syncthreads();
    const int ci2 = t & 63, lg = t >> 6;
#pragma unroll
    for (int k = 0; k < 16; ++k) {
        const int li2 = lg * 16 + k;
        yT[((size_t)b * NL + l0 + li2) * ND + c0 + ci2] = tile[ci2][li2];
    }
}

// --------------------------- K3: mixed[b][o][l] = bf16( (W @ y)[o][l] + b_mix[o] )
__global__ __launch_bounds__(256) void gemm_kernel(const unsigned short* __restrict__ wbf,
                                                   const unsigned short* __restrict__ yT,
                                                   const float* __restrict__ bmix,
                                                   unsigned short* __restrict__ mixed) {
    __shared__ unsigned short As[BM][BK];  // 8 KiB, linear [row][k]
    __shared__ unsigned short Bs[BN][BK];  // 8 KiB, linear [n][k]

    const int n0 = blockIdx.x * BN;
    const int m0 = blockIdx.y * BM;
    const int b = blockIdx.z;
    const int t = threadIdx.x;
    const int lane = t & 63, wid = t >> 6;
    const int wr = wid >> 1, wc = wid & 1;  // 2x2 waves, each 64x64
    const int fr = lane & 15;
    const int fk = (lane >> 4) * 8;

    const int srow = wid * 32 + (lane >> 2);
    const int sk = (lane & 3) * 8;
    const unsigned short* Ag = wbf + (size_t)(m0 + srow) * ND + sk;
    const unsigned short* Bg = yT + ((size_t)b * NL + n0 + srow) * ND + sk;
    unsigned short* AsD0 = &As[wid * 32][0];
    unsigned short* AsD1 = &As[wid * 32 + 16][0];
    unsigned short* BsD0 = &Bs[wid * 32][0];
    unsigned short* BsD1 = &Bs[wid * 32 + 16][0];

    f32x4 acc[4][4];
#pragma unroll
    for (int mi = 0; mi < 4; ++mi)
#pragma unroll
        for (int ni = 0; ni < 4; ++ni)
            acc[mi][ni] = (f32x4){0.f, 0.f, 0.f, 0.f};

    for (int kt = 0; kt < ND; kt += BK) {
        llds16(Ag + kt, AsD0);
        llds16(Ag + kt + 16 * ND, AsD1);
        llds16(Bg + kt, BsD0);
        llds16(Bg + kt + 16 * ND, BsD1);
        __syncthreads();

        bf16x8 af[4], bv[4];
#pragma unroll
        for (int mi = 0; mi < 4; ++mi)
            af[mi] = *reinterpret_cast<const bf16x8*>(&As[wr * 64 + mi * 16 + fr][fk]);
#pragma unroll
        for (int ni = 0; ni < 4; ++ni)
            bv[ni] = *reinterpret_cast<const bf16x8*>(&Bs[wc * 64 + ni * 16 + fr][fk]);
#pragma unroll
        for (int mi = 0; mi < 4; ++mi)
#pragma unroll
            for (int ni = 0; ni < 4; ++ni)
                acc[mi][ni] = __builtin_amdgcn_mfma_f32_16x16x32_bf16(af[mi], bv[ni],
                                                                      acc[mi][ni], 0, 0, 0);
        __syncthreads();
    }

    // epilogue: D[row][col], col = lane&15, row = (lane>>4)*4 + r
    const size_t bbase = (size_t)b * ND * NL;
#pragma unroll
    for (int mi = 0; mi < 4; ++mi) {
#pragma unroll
        for (int r = 0; r < 4; ++r) {
            const int o = m0 + wr * 64 + mi * 16 + (lane >> 4) * 4 + r;
            const float bm = bmix[o];
            const size_t rowbase = bbase + (size_t)o * NL;
#pragma unroll
            for (int ni = 0; ni < 4; ++ni) {
                const int l = n0 + wc * 64 + ni * 16 + fr;
                mixed[rowbase + l] = f2bf(acc[mi][ni][r] + bm);
            }
        }
    }
}

// ------------------------- K4: z = mixed + x (regs) -> LayerNorm over channels -> out
__global__ __launch_bounds__(512) void ln_kernel(const unsigned short* __restrict__ mixed,
                                                 const float* __restrict__ x,
                                                 const float* __restrict__ gamma,
                                                 const float* __restrict__ beta,
                                                 float* __restrict__ out) {
    const int b = blockIdx.y;
    const int l0 = blockIdx.x * 32;
    const int tl = threadIdx.x & 31, tg = threadIdx.x >> 5;  // 16 c-groups x 32 cols
    const size_t base = (size_t)b * ND * NL + l0 + tl;

    float zv[64];
    float s = 0.f, q = 0.f;
#pragma unroll
    for (int j = 0; j < 64; ++j) {
        const size_t idx = base + (size_t)(tg + j * 16) * NL;
        const float v = bf2f(mixed[idx]) + x[idx];
        zv[j] = v;
        s += v;
        q += v * v;
    }

    __shared__ float sred[16][33], qred[16][33];
    __shared__ float mu_s[32], rs_s[32];
    sred[tg][tl] = s;
    qred[tg][tl] = q;
    __syncthreads();
    if (tg == 0) {
        float S = 0.f, Q = 0.f;
#pragma unroll
        for (int g = 0; g < 16; ++g) {
            S += sred[g][tl];
            Q += qred[g][tl];
        }
        const float mu = S * (1.f / ND);
        const float var = Q * (1.f / ND) - mu * mu;
        mu_s[tl] = mu;
        rs_s[tl] = rsqrtf(var + LN_EPS);
    }
    __syncthreads();
    const float mu = mu_s[tl], rs = rs_s[tl];
#pragma unroll
    for (int j = 0; j < 64; ++j) {
        const int c = tg + j * 16;
        out[base + (size_t)c * NL] = (zv[j] - mu) * rs * gamma[c] + beta[c];
    }
}

extern "C" void kernel_launch(void* const* d_in, const int* in_sizes, int n_in,
                              void* d_out, int out_size, void* d_ws, size_t ws_size,
                              hipStream_t stream) {
    (void)in_sizes; (void)n_in; (void)out_size; (void)ws_size;
    const float* x = (const float*)d_in[0];
    const float* h0 = (const float*)d_in[1];
    const float* h1 = (const float*)d_in[2];
    const float* wmix = (const float*)d_in[3];
    const float* bmix = (const float*)d_in[4];
    const float* gamma = (const float*)d_in[5];
    const float* beta = (const float*)d_in[6];
    float* out = (float*)d_out;

    char* ws = (char*)d_ws;
    unsigned short* ybf = (unsigned short*)(ws);                              // 16 MiB
    unsigned short* yT = (unsigned short*)(ws + (size_t)16 * 1024 * 1024);    // 16 MiB
    unsigned short* wbf = (unsigned short*)(ws + (size_t)32 * 1024 * 1024);   // 2 MiB
    unsigned short* mixed = (unsigned short*)(ws + (size_t)34 * 1024 * 1024); // 16 MiB

    wconv_kernel<<<dim3(ND * ND / (256 * 8)), 256, 0, stream>>>(wmix, wbf);
    conv_cascade_kernel<<<dim3(NB * ND), 256, 0, stream>>>(x, h0, h1, ybf);
    transpose_kernel<<<dim3(NL / 64, ND / 64, NB), 256, 0, stream>>>(ybf, yT);
    gemm_kernel<<<dim3(NL / BN, ND / BM, NB), 256, 0, stream>>>(wbf, yT, bmix, mixed);
    ln_kernel<<<dim3(NL / 32, NB), 512, 0, stream>>>(mixed, x, gamma, beta, out);
}

// Round 6
// 108.746 us; speedup vs baseline: 2.1213x; 1.0008x over previous
//
#include <hip/hip_runtime.h>
#include <hip/hip_bf16.h>

#define NB 2
#define ND 1024
#define NL 4096
#define NFS 4
#define NDEPTH 11
#define LN_EPS 1e-5f

#define BM 128
#define BN 128
#define BK 32
#define NKI (ND / BK)

#define CPAD 384           // 3*dil at last LDS level (lev 7, dil=128)
#define CBUF (CPAD + NL)   // one conv buffer (4480 floats)

typedef __bf16 bf16x8 __attribute__((ext_vector_type(8)));
typedef float f32x4 __attribute__((ext_vector_type(4)));

__device__ __forceinline__ unsigned short f2bf(float f) {
    __hip_bfloat16 h = __float2bfloat16(f);
    unsigned short u;
    __builtin_memcpy(&u, &h, 2);
    return u;
}

__device__ __forceinline__ float bf2f(unsigned short u) {
    unsigned int ui = (unsigned int)u << 16;
    float f;
    __builtin_memcpy(&f, &ui, 4);
    return f;
}

__device__ __forceinline__ unsigned int pack2bf(float lo, float hi) {
    return (unsigned int)f2bf(lo) | ((unsigned int)f2bf(hi) << 16);
}

// fast sigmoid: v_exp + raw v_rcp (avoids IEEE div_scale/div_fmas/div_fixup)
__device__ __forceinline__ float sigm(float v) {
    return __builtin_amdgcn_rcpf(1.f + __expf(-v));
}

// async global->LDS, 16B per lane (wave-uniform LDS base + lane*16)
__device__ __forceinline__ void llds16(const void* g, void* l) {
    __builtin_amdgcn_global_load_lds(
        (const __attribute__((address_space(1))) unsigned int*)g,
        (__attribute__((address_space(3))) unsigned int*)l, 16, 0, 0);
}

// ---------------------------------------------------------------- K0: W -> bf16
__global__ __launch_bounds__(256) void wconv_kernel(const float* __restrict__ w,
                                                    unsigned short* __restrict__ wbf) {
    const int idx8 = (blockIdx.x * 256 + threadIdx.x) * 8;
    const float4 v0 = *reinterpret_cast<const float4*>(w + idx8);
    const float4 v1 = *reinterpret_cast<const float4*>(w + idx8 + 4);
    uint4 o;
    o.x = pack2bf(v0.x, v0.y);
    o.y = pack2bf(v0.z, v0.w);
    o.z = pack2bf(v1.x, v1.y);
    o.w = pack2bf(v1.z, v1.w);
    *reinterpret_cast<uint4*>(wbf + idx8) = o;
}

// ------------------------------------------------- K1: dilated conv cascade + gating
// one block per (b*ND + d) row; 256 threads, thread t owns positions i*256+t.
// DOUBLE-BUFFERED LDS: level L reads buf rb, writes buf wb, then ONE barrier —
// it proves both (a) all reads of rb finished (reads precede barrier and are
// consumed by FMAs before the writes) and (b) all writes of wb visible.
// Levels 8..10 (dil = 256/512/1024 = multiples of the ownership stride) read taps
// from the thread's own cur[] registers: no LDS, no barriers.
__global__ __launch_bounds__(256) void conv_cascade_kernel(const float* __restrict__ x,
                                                           const float* __restrict__ h0,
                                                           const float* __restrict__ h1,
                                                           unsigned short* __restrict__ ybf) {
    __shared__ float a_sh[2 * CBUF];  // 35 KiB (two padded row buffers)
    const int row = blockIdx.x;       // b*ND + d
    const int d = row & (ND - 1);
    const int t = threadIdx.x;

    // zero both pads (never written again)
#pragma unroll
    for (int j = 0; j < 2; ++j) {
        a_sh[j * CBUF + t] = 0.f;
        if (t < CPAD - 256) a_sh[j * CBUF + 256 + t] = 0.f;
    }

    const float* xrow = x + (size_t)row * NL;

    float h0c[NFS], h1c[NFS];
#pragma unroll
    for (int k = 0; k < NFS; ++k) {
        h0c[k] = h0[d * NFS + k];
        h1c[k] = h1[d * NFS + k];
    }

    float cur[16], yacc[16], bprev[16];
#pragma unroll
    for (int i = 0; i < 16; ++i) {
        cur[i] = xrow[i * 256 + t];
        a_sh[CPAD + i * 256 + t] = cur[i];  // stage x into buffer 0
        yacc[i] = 0.f;
        bprev[i] = 0.f;
    }
    __syncthreads();

    int rb = 0, wb = CBUF;  // read-buffer / write-buffer base offsets
    int dil = 1;
#pragma unroll 1
    for (int lev = 0; lev < 7; ++lev) {
        const int off1 = rb + CPAD + t - dil;
        const int off2 = rb + CPAD + t - 2 * dil;
        const int off3 = rb + CPAD + t - 3 * dil;
        float anew[16], bnew[16];
#pragma unroll
        for (int i = 0; i < 16; ++i) {
            const float a0 = cur[i];
            const float a1 = a_sh[off1 + i * 256];
            const float a2 = a_sh[off2 + i * 256];
            const float a3 = a_sh[off3 + i * 256];
            anew[i] = h0c[3] * a0 + h0c[2] * a1 + h0c[1] * a2 + h0c[0] * a3;
            bnew[i] = h1c[3] * a0 + h1c[2] * a1 + h1c[1] * a2 + h1c[0] * a3;
        }
#pragma unroll
        for (int i = 0; i < 16; ++i) a_sh[wb + CPAD + i * 256 + t] = anew[i];

        if (lev >= 1) {
            const float sc = (lev == 1) ? 2.f : 1.f;
#pragma unroll
            for (int i = 0; i < 16; ++i)
                yacc[i] += sc * sigm(anew[i]) * bprev[i];
        }
#pragma unroll
        for (int i = 0; i < 16; ++i) {
            cur[i] = anew[i];
            bprev[i] = bnew[i];
        }
        dil <<= 1;
        const int tmp = rb; rb = wb; wb = tmp;
        __syncthreads();  // single barrier per level (dbuf)
    }

    // lev 7 (dil=128): LDS taps from rb, no write-back (lev 8+ registers only)
    {
        const int off1 = rb + CPAD + t - 128;
        const int off2 = rb + CPAD + t - 256;
        const int off3 = rb + CPAD + t - 384;
        float anew[16], bnew[16];
#pragma unroll
        for (int i = 0; i < 16; ++i) {
            const float a0 = cur[i];
            const float a1 = a_sh[off1 + i * 256];
            const float a2 = a_sh[off2 + i * 256];
            const float a3 = a_sh[off3 + i * 256];
            anew[i] = h0c[3] * a0 + h0c[2] * a1 + h0c[1] * a2 + h0c[0] * a3;
            bnew[i] = h1c[3] * a0 + h1c[2] * a1 + h1c[1] * a2 + h1c[0] * a3;
        }
#pragma unroll
        for (int i = 0; i < 16; ++i) {
            yacc[i] += sigm(anew[i]) * bprev[i];
            cur[i] = anew[i];
            bprev[i] = bnew[i];
        }
    }

    // lev 8 (dil=256): taps = cur[i-1..i-3]
    {
        float anew[16], bnew[16];
#pragma unroll
        for (int i = 0; i < 16; ++i) {
            const float a0 = cur[i];
            const float a1 = (i >= 1) ? cur[i - 1] : 0.f;
            const float a2 = (i >= 2) ? cur[i - 2] : 0.f;
            const float a3 = (i >= 3) ? cur[i - 3] : 0.f;
            anew[i] = h0c[3] * a0 + h0c[2] * a1 + h0c[1] * a2 + h0c[0] * a3;
            bnew[i] = h1c[3] * a0 + h1c[2] * a1 + h1c[1] * a2 + h1c[0] * a3;
        }
#pragma unroll
        for (int i = 0; i < 16; ++i) {
            yacc[i] += sigm(anew[i]) * bprev[i];
            cur[i] = anew[i];
            bprev[i] = bnew[i];
        }
    }

    // lev 9 (dil=512): taps = cur[i-2], cur[i-4], cur[i-6]
    {
        float anew[16], bnew[16];
#pragma unroll
        for (int i = 0; i < 16; ++i) {
            const float a0 = cur[i];
            const float a1 = (i >= 2) ? cur[i - 2] : 0.f;
            const float a2 = (i >= 4) ? cur[i - 4] : 0.f;
            const float a3 = (i >= 6) ? cur[i - 6] : 0.f;
            anew[i] = h0c[3] * a0 + h0c[2] * a1 + h0c[1] * a2 + h0c[0] * a3;
            bnew[i] = h1c[3] * a0 + h1c[2] * a1 + h1c[1] * a2 + h1c[0] * a3;
        }
#pragma unroll
        for (int i = 0; i < 16; ++i) {
            yacc[i] += sigm(anew[i]) * bprev[i];
            cur[i] = anew[i];
            bprev[i] = bnew[i];
        }
    }

    // lev 10 (dil=1024): taps = cur[i-4], cur[i-8], cur[i-12]; b-conv dead (unused)
#pragma unroll
    for (int i = 0; i < 16; ++i) {
        const float a0 = cur[i];
        const float a1 = (i >= 4) ? cur[i - 4] : 0.f;
        const float a2 = (i >= 8) ? cur[i - 8] : 0.f;
        const float a3 = (i >= 12) ? cur[i - 12] : 0.f;
        const float an = h0c[3] * a0 + h0c[2] * a1 + h0c[1] * a2 + h0c[0] * a3;
        yacc[i] += sigm(an) * bprev[i];
    }

#pragma unroll
    for (int i = 0; i < 16; ++i)
        ybf[(size_t)row * NL + i * 256 + t] = f2bf(yacc[i]);
}

// ------------------------------------------- K2: y [b][c][l] bf16 -> yT [b][l][c] bf16
__global__ __launch_bounds__(256) void transpose_kernel(const unsigned short* __restrict__ ybf,
                                                        unsigned short* __restrict__ yT) {
    __shared__ unsigned short tile[64][66];
    const int l0 = blockIdx.x * 64;
    const int c0 = blockIdx.y * 64;
    const int b = blockIdx.z;
    const int t = threadIdx.x;
    const int li = t & 63, cg = t >> 6;
#pragma unroll
    for (int k = 0; k < 16; ++k) {
        const int ci = cg * 16 + k;
        tile[ci][li] = ybf[(size_t)(b * ND + c0 + ci) * NL + l0 + li];
    }
    __syncthreads();
    const int ci2 = t & 63, lg = t >> 6;
#pragma unroll
    for (int k = 0; k < 16; ++k) {
        const int li2 = lg * 16 + k;
        yT[((size_t)b * NL + l0 + li2) * ND + c0 + ci2] = tile[ci2][li2];
    }
}

// --------------------------- K3: mixed[b][o][l] = bf16( (W @ y)[o][l] + b_mix[o] )
// 2-phase prefetch: dbuf LDS; next tile's global_load_lds issued BEFORE current
// tile's ds_read+MFMA; raw s_barrier + hand vmcnt(0) so the prefetch stays in
// flight under the compute (compiler __syncthreads would drain it immediately).
__global__ __launch_bounds__(256) void gemm_kernel(const unsigned short* __restrict__ wbf,
                                                   const unsigned short* __restrict__ yT,
                                                   const float* __restrict__ bmix,
                                                   unsigned short* __restrict__ mixed) {
    __shared__ unsigned short As[2][BM][BK];  // 16 KiB
    __shared__ unsigned short Bs[2][BN][BK];  // 16 KiB

    const int n0 = blockIdx.x * BN;
    const int m0 = blockIdx.y * BM;
    const int b = blockIdx.z;
    const int t = threadIdx.x;
    const int lane = t & 63, wid = t >> 6;
    const int wr = wid >> 1, wc = wid & 1;  // 2x2 waves, each 64x64
    const int fr = lane & 15;
    const int fk = (lane >> 4) * 8;

    const int srow = wid * 32 + (lane >> 2);
    const int sk = (lane & 3) * 8;
    const unsigned short* Ag = wbf + (size_t)(m0 + srow) * ND + sk;
    const unsigned short* Bg = yT + ((size_t)b * NL + n0 + srow) * ND + sk;
    unsigned short* AsD0[2] = {&As[0][wid * 32][0], &As[1][wid * 32][0]};
    unsigned short* AsD1[2] = {&As[0][wid * 32 + 16][0], &As[1][wid * 32 + 16][0]};
    unsigned short* BsD0[2] = {&Bs[0][wid * 32][0], &Bs[1][wid * 32][0]};
    unsigned short* BsD1[2] = {&Bs[0][wid * 32 + 16][0], &Bs[1][wid * 32 + 16][0]};

    f32x4 acc[4][4];
#pragma unroll
    for (int mi = 0; mi < 4; ++mi)
#pragma unroll
        for (int ni = 0; ni < 4; ++ni)
            acc[mi][ni] = (f32x4){0.f, 0.f, 0.f, 0.f};

    // prologue: stage tile 0 into buf 0
    llds16(Ag, AsD0[0]);
    llds16(Ag + 16 * ND, AsD1[0]);
    llds16(Bg, BsD0[0]);
    llds16(Bg + 16 * ND, BsD1[0]);
    asm volatile("s_waitcnt vmcnt(0)" ::: "memory");
    __builtin_amdgcn_s_barrier();

    int cur = 0;
#pragma unroll 1
    for (int ki = 0; ki < NKI; ++ki) {
        if (ki + 1 < NKI) {  // prefetch next tile into the other buffer
            const int kt = (ki + 1) * BK;
            llds16(Ag + kt, AsD0[cur ^ 1]);
            llds16(Ag + kt + 16 * ND, AsD1[cur ^ 1]);
            llds16(Bg + kt, BsD0[cur ^ 1]);
            llds16(Bg + kt + 16 * ND, BsD1[cur ^ 1]);
        }

        bf16x8 af[4], bv[4];
#pragma unroll
        for (int mi = 0; mi < 4; ++mi)
            af[mi] = *reinterpret_cast<const bf16x8*>(&As[cur][wr * 64 + mi * 16 + fr][fk]);
#pragma unroll
        for (int ni = 0; ni < 4; ++ni)
            bv[ni] = *reinterpret_cast<const bf16x8*>(&Bs[cur][wc * 64 + ni * 16 + fr][fk]);
#pragma unroll
        for (int mi = 0; mi < 4; ++mi)
#pragma unroll
            for (int ni = 0; ni < 4; ++ni)
                acc[mi][ni] = __builtin_amdgcn_mfma_f32_16x16x32_bf16(af[mi], bv[ni],
                                                                      acc[mi][ni], 0, 0, 0);

        asm volatile("s_waitcnt vmcnt(0)" ::: "memory");  // prefetch landed
        __builtin_amdgcn_s_barrier();                     // all waves agree
        cur ^= 1;
    }

    // epilogue: D[row][col], col = lane&15, row = (lane>>4)*4 + r
    const size_t bbase = (size_t)b * ND * NL;
#pragma unroll
    for (int mi = 0; mi < 4; ++mi) {
#pragma unroll
        for (int r = 0; r < 4; ++r) {
            const int o = m0 + wr * 64 + mi * 16 + (lane >> 4) * 4 + r;
            const float bm = bmix[o];
            const size_t rowbase = bbase + (size_t)o * NL;
#pragma unroll
            for (int ni = 0; ni < 4; ++ni) {
                const int l = n0 + wc * 64 + ni * 16 + fr;
                mixed[rowbase + l] = f2bf(acc[mi][ni][r] + bm);
            }
        }
    }
}

// ------------------------- K4: z = mixed + x (regs) -> LayerNorm over channels -> out
__global__ __launch_bounds__(512) void ln_kernel(const unsigned short* __restrict__ mixed,
                                                 const float* __restrict__ x,
                                                 const float* __restrict__ gamma,
                                                 const float* __restrict__ beta,
                                                 float* __restrict__ out) {
    const int b = blockIdx.y;
    const int l0 = blockIdx.x * 32;
    const int tl = threadIdx.x & 31, tg = threadIdx.x >> 5;  // 16 c-groups x 32 cols
    const size_t base = (size_t)b * ND * NL + l0 + tl;

    float zv[64];
    float s = 0.f, q = 0.f;
#pragma unroll
    for (int j = 0; j < 64; ++j) {
        const size_t idx = base + (size_t)(tg + j * 16) * NL;
        const float v = bf2f(mixed[idx]) + x[idx];
        zv[j] = v;
        s += v;
        q += v * v;
    }

    __shared__ float sred[16][33], qred[16][33];
    __shared__ float mu_s[32], rs_s[32];
    sred[tg][tl] = s;
    qred[tg][tl] = q;
    __syncthreads();
    if (tg == 0) {
        float S = 0.f, Q = 0.f;
#pragma unroll
        for (int g = 0; g < 16; ++g) {
            S += sred[g][tl];
            Q += qred[g][tl];
        }
        const float mu = S * (1.f / ND);
        const float var = Q * (1.f / ND) - mu * mu;
        mu_s[tl] = mu;
        rs_s[tl] = rsqrtf(var + LN_EPS);
    }
    __syncthreads();
    const float mu = mu_s[tl], rs = rs_s[tl];
#pragma unroll
    for (int j = 0; j < 64; ++j) {
        const int c = tg + j * 16;
        out[base + (size_t)c * NL] = (zv[j] - mu) * rs * gamma[c] + beta[c];
    }
}

extern "C" void kernel_launch(void* const* d_in, const int* in_sizes, int n_in,
                              void* d_out, int out_size, void* d_ws, size_t ws_size,
                              hipStream_t stream) {
    (void)in_sizes; (void)n_in; (void)out_size; (void)ws_size;
    const float* x = (const float*)d_in[0];
    const float* h0 = (const float*)d_in[1];
    const float* h1 = (const float*)d_in[2];
    const float* wmix = (const float*)d_in[3];
    const float* bmix = (const float*)d_in[4];
    const float* gamma = (const float*)d_in[5];
    const float* beta = (const float*)d_in[6];
    float* out = (float*)d_out;

    char* ws = (char*)d_ws;
    unsigned short* ybf = (unsigned short*)(ws);                              // 16 MiB
    unsigned short* yT = (unsigned short*)(ws + (size_t)16 * 1024 * 1024);    // 16 MiB
    unsigned short* wbf = (unsigned short*)(ws + (size_t)32 * 1024 * 1024);   // 2 MiB
    unsigned short* mixed = (unsigned short*)(ws + (size_t)34 * 1024 * 1024); // 16 MiB

    wconv_kernel<<<dim3(ND * ND / (256 * 8)), 256, 0, stream>>>(wmix, wbf);
    conv_cascade_kernel<<<dim3(NB * ND), 256, 0, stream>>>(x, h0, h1, ybf);
    transpose_kernel<<<dim3(NL / 64, ND / 64, NB), 256, 0, stream>>>(ybf, yT);
    gemm_kernel<<<dim3(NL / BN, ND / BM, NB), 256, 0, stream>>>(wbf, yT, bmix, mixed);
    ln_kernel<<<dim3(NL / 32, NB), 512, 0, stream>>>(mixed, x, gamma, beta, out);
}

// Round 7
// 105.828 us; speedup vs baseline: 2.1798x; 1.0276x over previous
//
#include <hip/hip_runtime.h>
#include <hip/hip_bf16.h>

#define NB 2
#define ND 1024
#define NL 4096
#define NFS 4
#define NDEPTH 11
#define LN_EPS 1e-5f

#define BM 128
#define BN 128
#define BK 32
#define NKI (ND / BK)

#define CPAD 1536          // 3*dil at last LDS level (lev 9, dil=512)
#define CBUF (CPAD + NL)   // one conv buffer (5632 floats)

typedef __bf16 bf16x8 __attribute__((ext_vector_type(8)));
typedef float f32x4 __attribute__((ext_vector_type(4)));

__device__ __forceinline__ unsigned short f2bf(float f) {
    __hip_bfloat16 h = __float2bfloat16(f);
    unsigned short u;
    __builtin_memcpy(&u, &h, 2);
    return u;
}

__device__ __forceinline__ float bf2f(unsigned short u) {
    unsigned int ui = (unsigned int)u << 16;
    float f;
    __builtin_memcpy(&f, &ui, 4);
    return f;
}

__device__ __forceinline__ unsigned int pack2bf(float lo, float hi) {
    return (unsigned int)f2bf(lo) | ((unsigned int)f2bf(hi) << 16);
}

// fast sigmoid: v_exp + raw v_rcp (avoids IEEE div sequence)
__device__ __forceinline__ float sigm(float v) {
    return __builtin_amdgcn_rcpf(1.f + __expf(-v));
}

// async global->LDS, 16B per lane (wave-uniform LDS base + lane*16)
__device__ __forceinline__ void llds16(const void* g, void* l) {
    __builtin_amdgcn_global_load_lds(
        (const __attribute__((address_space(1))) unsigned int*)g,
        (__attribute__((address_space(3))) unsigned int*)l, 16, 0, 0);
}

// ---------------------------------------------------------------- K0: W -> bf16
__global__ __launch_bounds__(256) void wconv_kernel(const float* __restrict__ w,
                                                    unsigned short* __restrict__ wbf) {
    const int idx8 = (blockIdx.x * 256 + threadIdx.x) * 8;
    const float4 v0 = *reinterpret_cast<const float4*>(w + idx8);
    const float4 v1 = *reinterpret_cast<const float4*>(w + idx8 + 4);
    uint4 o;
    o.x = pack2bf(v0.x, v0.y);
    o.y = pack2bf(v0.z, v0.w);
    o.z = pack2bf(v1.x, v1.y);
    o.w = pack2bf(v1.z, v1.w);
    *reinterpret_cast<uint4*>(wbf + idx8) = o;
}

// ------------------------------------------------- K1: dilated conv cascade + gating
// one block per (b*ND + d) row; 256 threads. Thread t owns 4 CHUNKS of 4 contiguous
// positions: chunk c covers [c*1024 + t*4, +4). All LDS tap traffic is ds_read_b128 /
// ds_write_b128 (conflict-free: lanes hit consecutive 16B blocks). For dil multiple
// of 4 the three tap groups are direct aligned b128 reads; dil=1,2 read the adjacent
// aligned block and statically mix with own registers. Lev 10 (dil=1024 = chunk
// stride) is register-local. Double-buffered LDS: one barrier per level.
__global__ __launch_bounds__(256) void conv_cascade_kernel(const float* __restrict__ x,
                                                           const float* __restrict__ h0,
                                                           const float* __restrict__ h1,
                                                           unsigned short* __restrict__ ybf) {
    __shared__ float a_sh[2 * CBUF];  // 45056 B
    const int row = blockIdx.x;       // b*ND + d
    const int d = row & (ND - 1);
    const int t = threadIdx.x;

    // zero both pads (never written again)
#pragma unroll
    for (int j = 0; j < 2; ++j)
#pragma unroll
        for (int i = 0; i < CPAD / 256; ++i)
            a_sh[j * CBUF + i * 256 + t] = 0.f;

    const float* xrow = x + (size_t)row * NL;

    float h0c[NFS], h1c[NFS];
#pragma unroll
    for (int k = 0; k < NFS; ++k) {
        h0c[k] = h0[d * NFS + k];
        h1c[k] = h1[d * NFS + k];
    }

    float cur[4][4], yacc[4][4], bprev[4][4];
#pragma unroll
    for (int c = 0; c < 4; ++c) {
        const float4 v = *reinterpret_cast<const float4*>(xrow + c * 1024 + t * 4);
        cur[c][0] = v.x; cur[c][1] = v.y; cur[c][2] = v.z; cur[c][3] = v.w;
        *reinterpret_cast<float4*>(&a_sh[CPAD + c * 1024 + t * 4]) = v;
#pragma unroll
        for (int j = 0; j < 4; ++j) { yacc[c][j] = 0.f; bprev[c][j] = 0.f; }
    }
    __syncthreads();

    int rb = 0, wb = CBUF;

// computes anew/bnew from taps, writes back anew, gates (sc), updates cur/bprev
#define CONV_CHUNK(c, A1, A2, A3, SC, WB)                                            \
    {                                                                                \
        float an[4], bn[4];                                                          \
        _Pragma("unroll") for (int j = 0; j < 4; ++j) {                              \
            an[j] = h0c[3] * cur[c][j] + h0c[2] * (A1)[j] + h0c[1] * (A2)[j] +       \
                    h0c[0] * (A3)[j];                                                \
            bn[j] = h1c[3] * cur[c][j] + h1c[2] * (A1)[j] + h1c[1] * (A2)[j] +       \
                    h1c[0] * (A3)[j];                                                \
        }                                                                            \
        if (WB) {                                                                    \
            float4 wv; wv.x = an[0]; wv.y = an[1]; wv.z = an[2]; wv.w = an[3];       \
            *reinterpret_cast<float4*>(&a_sh[wb + CPAD + (c)*1024 + t * 4]) = wv;    \
        }                                                                            \
        if ((SC) > 0.f) {                                                            \
            _Pragma("unroll") for (int j = 0; j < 4; ++j)                            \
                yacc[c][j] += (SC)*sigm(an[j]) * bprev[c][j];                        \
        }                                                                            \
        _Pragma("unroll") for (int j = 0; j < 4; ++j) {                              \
            cur[c][j] = an[j];                                                       \
            bprev[c][j] = bn[j];                                                     \
        }                                                                            \
    }

    // ---- lev 0 (dil=1): 1 aligned block read + static mix, no gate
#pragma unroll
    for (int c = 0; c < 4; ++c) {
        const int A = rb + CPAD + c * 1024 + t * 4;
        const float4 m1 = *reinterpret_cast<const float4*>(&a_sh[A - 4]);  // [-4..-1]
        const float a1[4] = {m1.w, cur[c][0], cur[c][1], cur[c][2]};
        const float a2[4] = {m1.z, m1.w, cur[c][0], cur[c][1]};
        const float a3[4] = {m1.y, m1.z, m1.w, cur[c][0]};
        CONV_CHUNK(c, a1, a2, a3, 0.f, 1)
    }
    { const int tmp = rb; rb = wb; wb = tmp; }
    __syncthreads();

    // ---- lev 1 (dil=2): 2 aligned block reads + static mix, gate x2
#pragma unroll
    for (int c = 0; c < 4; ++c) {
        const int A = rb + CPAD + c * 1024 + t * 4;
        const float4 m1 = *reinterpret_cast<const float4*>(&a_sh[A - 4]);  // [-4..-1]
        const float4 m2 = *reinterpret_cast<const float4*>(&a_sh[A - 8]);  // [-8..-5]
        const float a1[4] = {m1.z, m1.w, cur[c][0], cur[c][1]};
        const float a2[4] = {m1.x, m1.y, m1.z, m1.w};
        const float a3[4] = {m2.z, m2.w, m1.x, m1.y};
        CONV_CHUNK(c, a1, a2, a3, 2.f, 1)
    }
    { const int tmp = rb; rb = wb; wb = tmp; }
    __syncthreads();

    // ---- lev 2..8 (dil=4..256): 3 direct aligned b128 reads, gate, write-back
    int dil = 4;
#pragma unroll 1
    for (int lev = 2; lev <= 8; ++lev) {
#pragma unroll
        for (int c = 0; c < 4; ++c) {
            const int A = rb + CPAD + c * 1024 + t * 4;
            const float4 b1 = *reinterpret_cast<const float4*>(&a_sh[A - dil]);
            const float4 b2 = *reinterpret_cast<const float4*>(&a_sh[A - 2 * dil]);
            const float4 b3 = *reinterpret_cast<const float4*>(&a_sh[A - 3 * dil]);
            const float a1[4] = {b1.x, b1.y, b1.z, b1.w};
            const float a2[4] = {b2.x, b2.y, b2.z, b2.w};
            const float a3[4] = {b3.x, b3.y, b3.z, b3.w};
            CONV_CHUNK(c, a1, a2, a3, 1.f, 1)
        }
        { const int tmp = rb; rb = wb; wb = tmp; }
        dil <<= 1;
        __syncthreads();
    }

    // ---- lev 9 (dil=512): 3 direct reads, gate, NO write-back
#pragma unroll
    for (int c = 0; c < 4; ++c) {
        const int A = rb + CPAD + c * 1024 + t * 4;
        const float4 b1 = *reinterpret_cast<const float4*>(&a_sh[A - 512]);
        const float4 b2 = *reinterpret_cast<const float4*>(&a_sh[A - 1024]);
        const float4 b3 = *reinterpret_cast<const float4*>(&a_sh[A - 1536]);
        const float a1[4] = {b1.x, b1.y, b1.z, b1.w};
        const float a2[4] = {b2.x, b2.y, b2.z, b2.w};
        const float a3[4] = {b3.x, b3.y, b3.z, b3.w};
        CONV_CHUNK(c, a1, a2, a3, 1.f, 0)
    }

    // ---- lev 10 (dil=1024 = chunk stride): register-local; b-conv dead; cur not
    //      overwritten (later chunks need earlier chunks' pre-lev10 cur)
#pragma unroll
    for (int c = 0; c < 4; ++c) {
#pragma unroll
        for (int j = 0; j < 4; ++j) {
            const float a1 = (c >= 1) ? cur[c - 1][j] : 0.f;
            const float a2 = (c >= 2) ? cur[c - 2][j] : 0.f;
            const float a3 = (c >= 3) ? cur[c - 3][j] : 0.f;
            const float an = h0c[3] * cur[c][j] + h0c[2] * a1 + h0c[1] * a2 + h0c[0] * a3;
            yacc[c][j] += sigm(an) * bprev[c][j];
        }
    }
#undef CONV_CHUNK

#pragma unroll
    for (int c = 0; c < 4; ++c) {
        ushort4 o;
        o.x = f2bf(yacc[c][0]);
        o.y = f2bf(yacc[c][1]);
        o.z = f2bf(yacc[c][2]);
        o.w = f2bf(yacc[c][3]);
        *reinterpret_cast<ushort4*>(ybf + (size_t)row * NL + c * 1024 + t * 4) = o;
    }
}

// ------------------------------------------- K2: y [b][c][l] bf16 -> yT [b][l][c] bf16
__global__ __launch_bounds__(256) void transpose_kernel(const unsigned short* __restrict__ ybf,
                                                        unsigned short* __restrict__ yT) {
    __shared__ unsigned short tile[64][66];
    const int l0 = blockIdx.x * 64;
    const int c0 = blockIdx.y * 64;
    const int b = blockIdx.z;
    const int t = threadIdx.x;
    const int li = t & 63, cg = t >> 6;
#pragma unroll
    for (int k = 0; k < 16; ++k) {
        const int ci = cg * 16 + k;
        tile[ci][li] = ybf[(size_t)(b * ND + c0 + ci) * NL + l0 + li];
    }
    __syncthreads();
    const int ci2 = t & 63, lg = t >> 6;
#pragma unroll
    for (int k = 0; k < 16; ++k) {
        const int li2 = lg * 16 + k;
        yT[((size_t)b * NL + l0 + li2) * ND + c0 + ci2] = tile[ci2][li2];
    }
}

// --------------------------- K3: mixed[b][o][l] = bf16( (W @ y)[o][l] + b_mix[o] )
__global__ __launch_bounds__(256) void gemm_kernel(const unsigned short* __restrict__ wbf,
                                                   const unsigned short* __restrict__ yT,
                                                   const float* __restrict__ bmix,
                                                   unsigned short* __restrict__ mixed) {
    __shared__ unsigned short As[2][BM][BK];  // 16 KiB
    __shared__ unsigned short Bs[2][BN][BK];  // 16 KiB

    const int n0 = blockIdx.x * BN;
    const int m0 = blockIdx.y * BM;
    const int b = blockIdx.z;
    const int t = threadIdx.x;
    const int lane = t & 63, wid = t >> 6;
    const int wr = wid >> 1, wc = wid & 1;  // 2x2 waves, each 64x64
    const int fr = lane & 15;
    const int fk = (lane >> 4) * 8;

    const int srow = wid * 32 + (lane >> 2);
    const int sk = (lane & 3) * 8;
    const unsigned short* Ag = wbf + (size_t)(m0 + srow) * ND + sk;
    const unsigned short* Bg = yT + ((size_t)b * NL + n0 + srow) * ND + sk;
    unsigned short* AsD0[2] = {&As[0][wid * 32][0], &As[1][wid * 32][0]};
    unsigned short* AsD1[2] = {&As[0][wid * 32 + 16][0], &As[1][wid * 32 + 16][0]};
    unsigned short* BsD0[2] = {&Bs[0][wid * 32][0], &Bs[1][wid * 32][0]};
    unsigned short* BsD1[2] = {&Bs[0][wid * 32 + 16][0], &Bs[1][wid * 32 + 16][0]};

    f32x4 acc[4][4];
#pragma unroll
    for (int mi = 0; mi < 4; ++mi)
#pragma unroll
        for (int ni = 0; ni < 4; ++ni)
            acc[mi][ni] = (f32x4){0.f, 0.f, 0.f, 0.f};

    // prologue: stage tile 0 into buf 0
    llds16(Ag, AsD0[0]);
    llds16(Ag + 16 * ND, AsD1[0]);
    llds16(Bg, BsD0[0]);
    llds16(Bg + 16 * ND, BsD1[0]);
    asm volatile("s_waitcnt vmcnt(0)" ::: "memory");
    __builtin_amdgcn_s_barrier();

    int cur = 0;
#pragma unroll 1
    for (int ki = 0; ki < NKI; ++ki) {
        if (ki + 1 < NKI) {  // prefetch next tile into the other buffer
            const int kt = (ki + 1) * BK;
            llds16(Ag + kt, AsD0[cur ^ 1]);
            llds16(Ag + kt + 16 * ND, AsD1[cur ^ 1]);
            llds16(Bg + kt, BsD0[cur ^ 1]);
            llds16(Bg + kt + 16 * ND, BsD1[cur ^ 1]);
        }

        bf16x8 af[4], bv[4];
#pragma unroll
        for (int mi = 0; mi < 4; ++mi)
            af[mi] = *reinterpret_cast<const bf16x8*>(&As[cur][wr * 64 + mi * 16 + fr][fk]);
#pragma unroll
        for (int ni = 0; ni < 4; ++ni)
            bv[ni] = *reinterpret_cast<const bf16x8*>(&Bs[cur][wc * 64 + ni * 16 + fr][fk]);
#pragma unroll
        for (int mi = 0; mi < 4; ++mi)
#pragma unroll
            for (int ni = 0; ni < 4; ++ni)
                acc[mi][ni] = __builtin_amdgcn_mfma_f32_16x16x32_bf16(af[mi], bv[ni],
                                                                      acc[mi][ni], 0, 0, 0);

        asm volatile("s_waitcnt vmcnt(0)" ::: "memory");  // prefetch landed
        __builtin_amdgcn_s_barrier();                     // all waves agree
        cur ^= 1;
    }

    // epilogue: D[row][col], col = lane&15, row = (lane>>4)*4 + r
    const size_t bbase = (size_t)b * ND * NL;
#pragma unroll
    for (int mi = 0; mi < 4; ++mi) {
#pragma unroll
        for (int r = 0; r < 4; ++r) {
            const int o = m0 + wr * 64 + mi * 16 + (lane >> 4) * 4 + r;
            const float bm = bmix[o];
            const size_t rowbase = bbase + (size_t)o * NL;
#pragma unroll
            for (int ni = 0; ni < 4; ++ni) {
                const int l = n0 + wc * 64 + ni * 16 + fr;
                mixed[rowbase + l] = f2bf(acc[mi][ni][r] + bm);
            }
        }
    }
}

// ------------------------- K4: z = mixed + x (regs) -> LayerNorm over channels -> out
__global__ __launch_bounds__(512) void ln_kernel(const unsigned short* __restrict__ mixed,
                                                 const float* __restrict__ x,
                                                 const float* __restrict__ gamma,
                                                 const float* __restrict__ beta,
                                                 float* __restrict__ out) {
    const int b = blockIdx.y;
    const int l0 = blockIdx.x * 32;
    const int tl = threadIdx.x & 31, tg = threadIdx.x >> 5;  // 16 c-groups x 32 cols
    const size_t base = (size_t)b * ND * NL + l0 + tl;

    float zv[64];
    float s = 0.f, q = 0.f;
#pragma unroll
    for (int j = 0; j < 64; ++j) {
        const size_t idx = base + (size_t)(tg + j * 16) * NL;
        const float v = bf2f(mixed[idx]) + x[idx];
        zv[j] = v;
        s += v;
        q += v * v;
    }

    __shared__ float sred[16][33], qred[16][33];
    __shared__ float mu_s[32], rs_s[32];
    sred[tg][tl] = s;
    qred[tg][tl] = q;
    __syncthreads();
    if (tg == 0) {
        float S = 0.f, Q = 0.f;
#pragma unroll
        for (int g = 0; g < 16; ++g) {
            S += sred[g][tl];
            Q += qred[g][tl];
        }
        const float mu = S * (1.f / ND);
        const float var = Q * (1.f / ND) - mu * mu;
        mu_s[tl] = mu;
        rs_s[tl] = rsqrtf(var + LN_EPS);
    }
    __syncthreads();
    const float mu = mu_s[tl], rs = rs_s[tl];
#pragma unroll
    for (int j = 0; j < 64; ++j) {
        const int c = tg + j * 16;
        out[base + (size_t)c * NL] = (zv[j] - mu) * rs * gamma[c] + beta[c];
    }
}

extern "C" void kernel_launch(void* const* d_in, const int* in_sizes, int n_in,
                              void* d_out, int out_size, void* d_ws, size_t ws_size,
                              hipStream_t stream) {
    (void)in_sizes; (void)n_in; (void)out_size; (void)ws_size;
    const float* x = (const float*)d_in[0];
    const float* h0 = (const float*)d_in[1];
    const float* h1 = (const float*)d_in[2];
    const float* wmix = (const float*)d_in[3];
    const float* bmix = (const float*)d_in[4];
    const float* gamma = (const float*)d_in[5];
    const float* beta = (const float*)d_in[6];
    float* out = (float*)d_out;

    char* ws = (char*)d_ws;
    unsigned short* ybf = (unsigned short*)(ws);                              // 16 MiB
    unsigned short* yT = (unsigned short*)(ws + (size_t)16 * 1024 * 1024);    // 16 MiB
    unsigned short* wbf = (unsigned short*)(ws + (size_t)32 * 1024 * 1024);   // 2 MiB
    unsigned short* mixed = (unsigned short*)(ws + (size_t)34 * 1024 * 1024); // 16 MiB

    wconv_kernel<<<dim3(ND * ND / (256 * 8)), 256, 0, stream>>>(wmix, wbf);
    conv_cascade_kernel<<<dim3(NB * ND), 256, 0, stream>>>(x, h0, h1, ybf);
    transpose_kernel<<<dim3(NL / 64, ND / 64, NB), 256, 0, stream>>>(ybf, yT);
    gemm_kernel<<<dim3(NL / BN, ND / BM, NB), 256, 0, stream>>>(wbf, yT, bmix, mixed);
    ln_kernel<<<dim3(NL / 32, NB), 512, 0, stream>>>(mixed, x, gamma, beta, out);
}

// Round 8
// 104.153 us; speedup vs baseline: 2.2148x; 1.0161x over previous
//
#include <hip/hip_runtime.h>
#include <hip/hip_bf16.h>

#define NB 2
#define ND 1024
#define NL 4096
#define NFS 4
#define NDEPTH 11
#define LN_EPS 1e-5f

#define BM 128
#define BN 128
#define BK 32
#define NKI (ND / BK)
#define ASZ (BM * BK)  // shorts per A (or B) buffer

#define CPAD 3072          // lev10 reads back 3*1024
#define CBUF (CPAD + NL)   // single conv buffer (7168 floats, 28 KiB)

typedef __bf16 bf16x8 __attribute__((ext_vector_type(8)));
typedef float f32x4 __attribute__((ext_vector_type(4)));

__device__ __forceinline__ unsigned short f2bf(float f) {
    __hip_bfloat16 h = __float2bfloat16(f);
    unsigned short u;
    __builtin_memcpy(&u, &h, 2);
    return u;
}

__device__ __forceinline__ float bf2f(unsigned short u) {
    unsigned int ui = (unsigned int)u << 16;
    float f;
    __builtin_memcpy(&f, &ui, 4);
    return f;
}

__device__ __forceinline__ unsigned int pack2bf(float lo, float hi) {
    return (unsigned int)f2bf(lo) | ((unsigned int)f2bf(hi) << 16);
}

// fast sigmoid: v_exp + raw v_rcp (avoids IEEE div sequence)
__device__ __forceinline__ float sigm(float v) {
    return __builtin_amdgcn_rcpf(1.f + __expf(-v));
}

// async global->LDS, 16B per lane (wave-uniform LDS base + lane*16)
__device__ __forceinline__ void llds16(const void* g, void* l) {
    __builtin_amdgcn_global_load_lds(
        (const __attribute__((address_space(1))) unsigned int*)g,
        (__attribute__((address_space(3))) unsigned int*)l, 16, 0, 0);
}

// ---------------------------------------------------------------- K0: W -> bf16
__global__ __launch_bounds__(256) void wconv_kernel(const float* __restrict__ w,
                                                    unsigned short* __restrict__ wbf) {
    const int idx8 = (blockIdx.x * 256 + threadIdx.x) * 8;
    const float4 v0 = *reinterpret_cast<const float4*>(w + idx8);
    const float4 v1 = *reinterpret_cast<const float4*>(w + idx8 + 4);
    uint4 o;
    o.x = pack2bf(v0.x, v0.y);
    o.y = pack2bf(v0.z, v0.w);
    o.z = pack2bf(v1.x, v1.y);
    o.w = pack2bf(v1.z, v1.w);
    *reinterpret_cast<uint4*>(wbf + idx8) = o;
}

// ------------------------------------------------- K1: dilated conv cascade + gating
// one block per (b*ND + d) row; 512 threads, thread t owns 2 chunks of 4 contiguous
// positions: chunk c covers [c*2048 + t*4, +4). Single in-place LDS buffer with a
// 3072-float zero pad (2 barriers/level: reads | barrier | writes | barrier).
// All tap traffic is ds_read_b128/ds_write_b128, conflict-free. Lev 10 (dil=1024):
// taps -1024/-3072 from LDS, -2048 = chunk stride -> register. b-conv at lev 10 dead.
// __launch_bounds__(512,8) forces VGPR<=64 -> 8 waves/SIMD, 4 blocks/CU (32 waves).
__global__ __launch_bounds__(512, 8) void conv_cascade_kernel(const float* __restrict__ x,
                                                              const float* __restrict__ h0,
                                                              const float* __restrict__ h1,
                                                              unsigned short* __restrict__ ybf) {
    __shared__ float a_sh[CBUF];  // 28672 B
    const int row = blockIdx.x;   // b*ND + d
    const int d = row & (ND - 1);
    const int t = threadIdx.x;

    // zero the pad (3072 = 6*512); never written again
#pragma unroll
    for (int i = 0; i < CPAD / 512; ++i) a_sh[i * 512 + t] = 0.f;

    const float* xrow = x + (size_t)row * NL;

    float h0c[NFS], h1c[NFS];
#pragma unroll
    for (int k = 0; k < NFS; ++k) {
        h0c[k] = h0[d * NFS + k];
        h1c[k] = h1[d * NFS + k];
    }

    float cur[2][4], yacc[2][4], bprev[2][4];
#pragma unroll
    for (int c = 0; c < 2; ++c) {
        const float4 v = *reinterpret_cast<const float4*>(xrow + c * 2048 + t * 4);
        cur[c][0] = v.x; cur[c][1] = v.y; cur[c][2] = v.z; cur[c][3] = v.w;
        *reinterpret_cast<float4*>(&a_sh[CPAD + c * 2048 + t * 4]) = v;
#pragma unroll
        for (int j = 0; j < 4; ++j) { yacc[c][j] = 0.f; bprev[c][j] = 0.f; }
    }
    __syncthreads();

// compute an/bn for chunk c from tap arrays (reads already done)
#define CONV_MATH(c, A1, A2, A3, an, bn)                                             \
    _Pragma("unroll") for (int j = 0; j < 4; ++j) {                                  \
        an[j] = h0c[3] * cur[c][j] + h0c[2] * (A1)[j] + h0c[1] * (A2)[j] +           \
                h0c[0] * (A3)[j];                                                    \
        bn[j] = h1c[3] * cur[c][j] + h1c[2] * (A1)[j] + h1c[1] * (A2)[j] +           \
                h1c[0] * (A3)[j];                                                    \
    }
// write-back + gate + state update for chunk c
#define CONV_FIN(c, an, bn, SC)                                                      \
    {                                                                                \
        float4 wv; wv.x = an[0]; wv.y = an[1]; wv.z = an[2]; wv.w = an[3];           \
        *reinterpret_cast<float4*>(&a_sh[CPAD + (c)*2048 + t * 4]) = wv;             \
        if ((SC) > 0.f) {                                                            \
            _Pragma("unroll") for (int j = 0; j < 4; ++j)                            \
                yacc[c][j] += (SC)*sigm(an[j]) * bprev[c][j];                        \
        }                                                                            \
        _Pragma("unroll") for (int j = 0; j < 4; ++j) {                              \
            cur[c][j] = an[j];                                                       \
            bprev[c][j] = bn[j];                                                     \
        }                                                                            \
    }

    float an0[4], bn0[4], an1[4], bn1[4];

    // ---- lev 0 (dil=1): 1 aligned block read/chunk + static mix, no gate
    {
        {
            const int A = CPAD + 0 * 2048 + t * 4;
            const float4 m1 = *reinterpret_cast<const float4*>(&a_sh[A - 4]);
            const float a1[4] = {m1.w, cur[0][0], cur[0][1], cur[0][2]};
            const float a2[4] = {m1.z, m1.w, cur[0][0], cur[0][1]};
            const float a3[4] = {m1.y, m1.z, m1.w, cur[0][0]};
            CONV_MATH(0, a1, a2, a3, an0, bn0)
        }
        {
            const int A = CPAD + 1 * 2048 + t * 4;
            const float4 m1 = *reinterpret_cast<const float4*>(&a_sh[A - 4]);
            const float a1[4] = {m1.w, cur[1][0], cur[1][1], cur[1][2]};
            const float a2[4] = {m1.z, m1.w, cur[1][0], cur[1][1]};
            const float a3[4] = {m1.y, m1.z, m1.w, cur[1][0]};
            CONV_MATH(1, a1, a2, a3, an1, bn1)
        }
        __syncthreads();
        CONV_FIN(0, an0, bn0, 0.f)
        CONV_FIN(1, an1, bn1, 0.f)
        __syncthreads();
    }

    // ---- lev 1 (dil=2): 2 aligned block reads/chunk + static mix, gate x2
    {
        {
            const int A = CPAD + 0 * 2048 + t * 4;
            const float4 m1 = *reinterpret_cast<const float4*>(&a_sh[A - 4]);
            const float4 m2 = *reinterpret_cast<const float4*>(&a_sh[A - 8]);
            const float a1[4] = {m1.z, m1.w, cur[0][0], cur[0][1]};
            const float a2[4] = {m1.x, m1.y, m1.z, m1.w};
            const float a3[4] = {m2.z, m2.w, m1.x, m1.y};
            CONV_MATH(0, a1, a2, a3, an0, bn0)
        }
        {
            const int A = CPAD + 1 * 2048 + t * 4;
            const float4 m1 = *reinterpret_cast<const float4*>(&a_sh[A - 4]);
            const float4 m2 = *reinterpret_cast<const float4*>(&a_sh[A - 8]);
            const float a1[4] = {m1.z, m1.w, cur[1][0], cur[1][1]};
            const float a2[4] = {m1.x, m1.y, m1.z, m1.w};
            const float a3[4] = {m2.z, m2.w, m1.x, m1.y};
            CONV_MATH(1, a1, a2, a3, an1, bn1)
        }
        __syncthreads();
        CONV_FIN(0, an0, bn0, 2.f)
        CONV_FIN(1, an1, bn1, 2.f)
        __syncthreads();
    }

    // ---- lev 2..9 (dil=4..512): 3 direct aligned b128 reads/chunk, gate, write-back
    int dil = 4;
#pragma unroll 1
    for (int lev = 2; lev <= 9; ++lev) {
        {
            const int A = CPAD + 0 * 2048 + t * 4;
            const float4 b1 = *reinterpret_cast<const float4*>(&a_sh[A - dil]);
            const float4 b2 = *reinterpret_cast<const float4*>(&a_sh[A - 2 * dil]);
            const float4 b3 = *reinterpret_cast<const float4*>(&a_sh[A - 3 * dil]);
            const float a1[4] = {b1.x, b1.y, b1.z, b1.w};
            const float a2[4] = {b2.x, b2.y, b2.z, b2.w};
            const float a3[4] = {b3.x, b3.y, b3.z, b3.w};
            CONV_MATH(0, a1, a2, a3, an0, bn0)
        }
        {
            const int A = CPAD + 1 * 2048 + t * 4;
            const float4 b1 = *reinterpret_cast<const float4*>(&a_sh[A - dil]);
            const float4 b2 = *reinterpret_cast<const float4*>(&a_sh[A - 2 * dil]);
            const float4 b3 = *reinterpret_cast<const float4*>(&a_sh[A - 3 * dil]);
            const float a1[4] = {b1.x, b1.y, b1.z, b1.w};
            const float a2[4] = {b2.x, b2.y, b2.z, b2.w};
            const float a3[4] = {b3.x, b3.y, b3.z, b3.w};
            CONV_MATH(1, a1, a2, a3, an1, bn1)
        }
        __syncthreads();
        CONV_FIN(0, an0, bn0, 1.f)
        CONV_FIN(1, an1, bn1, 1.f)
        dil <<= 1;
        __syncthreads();
    }

    // ---- lev 10 (dil=1024): taps -1024/-3072 from LDS (lev9 values), -2048 register.
    //      b-conv dead; no write-back; chunk 0's -2048 tap is in the zero pad.
#pragma unroll
    for (int c = 0; c < 2; ++c) {
        const int A = CPAD + c * 2048 + t * 4;
        const float4 b1 = *reinterpret_cast<const float4*>(&a_sh[A - 1024]);
        const float4 b3 = *reinterpret_cast<const float4*>(&a_sh[A - 3072]);
#pragma unroll
        for (int j = 0; j < 4; ++j) {
            const float a1 = (&b1.x)[j];
            const float a2 = (c == 1) ? cur[0][j] : 0.f;
            const float a3 = (&b3.x)[j];
            const float an = h0c[3] * cur[c][j] + h0c[2] * a1 + h0c[1] * a2 + h0c[0] * a3;
            yacc[c][j] += sigm(an) * bprev[c][j];
        }
    }
#undef CONV_MATH
#undef CONV_FIN

#pragma unroll
    for (int c = 0; c < 2; ++c) {
        ushort4 o;
        o.x = f2bf(yacc[c][0]);
        o.y = f2bf(yacc[c][1]);
        o.z = f2bf(yacc[c][2]);
        o.w = f2bf(yacc[c][3]);
        *reinterpret_cast<ushort4*>(ybf + (size_t)row * NL + c * 2048 + t * 4) = o;
    }
}

// ------------------------------------------- K2: y [b][c][l] bf16 -> yT [b][l][c] bf16
__global__ __launch_bounds__(256) void transpose_kernel(const unsigned short* __restrict__ ybf,
                                                        unsigned short* __restrict__ yT) {
    __shared__ unsigned short tile[64][66];
    const int l0 = blockIdx.x * 64;
    const int c0 = blockIdx.y * 64;
    const int b = blockIdx.z;
    const int t = threadIdx.x;
    const int li = t & 63, cg = t >> 6;
#pragma unroll
    for (int k = 0; k < 16; ++k) {
        const int ci = cg * 16 + k;
        tile[ci][li] = ybf[(size_t)(b * ND + c0 + ci) * NL + l0 + li];
    }
    __syncthreads();
    const int ci2 = t & 63, lg = t >> 6;
#pragma unroll
    for (int k = 0; k < 16; ++k) {
        const int li2 = lg * 16 + k;
        yT[((size_t)b * NL + l0 + li2) * ND + c0 + ci2] = tile[ci2][li2];
    }
}

// --------------------------- K3: mixed[b][o][l] = bf16( (W @ y)[o][l] + b_mix[o] )
// ring-3 LDS staging with counted vmcnt(4): 2 tiles in flight, never drained to 0
// inside the loop -> load latency hides under ~2 compute phases + co-resident blocks.
__global__ __launch_bounds__(256) void gemm_kernel(const unsigned short* __restrict__ wbf,
                                                   const unsigned short* __restrict__ yT,
                                                   const float* __restrict__ bmix,
                                                   unsigned short* __restrict__ mixed) {
    __shared__ unsigned short As[3][BM][BK];  // 24 KiB
    __shared__ unsigned short Bs[3][BN][BK];  // 24 KiB

    const int n0 = blockIdx.x * BN;
    const int m0 = blockIdx.y * BM;
    const int b = blockIdx.z;
    const int t = threadIdx.x;
    const int lane = t & 63, wid = t >> 6;
    const int wr = wid >> 1, wc = wid & 1;  // 2x2 waves, each 64x64
    const int fr = lane & 15;
    const int fk = (lane >> 4) * 8;

    const int srow = wid * 32 + (lane >> 2);
    const int sk = (lane & 3) * 8;
    const unsigned short* Ag = wbf + (size_t)(m0 + srow) * ND + sk;
    const unsigned short* Bg = yT + ((size_t)b * NL + n0 + srow) * ND + sk;
    unsigned short* A0 = &As[0][0][0];
    unsigned short* B0 = &Bs[0][0][0];
    unsigned short* AsW = A0 + wid * 32 * BK;  // wave's staging dest in buf 0
    unsigned short* BsW = B0 + wid * 32 * BK;

#define STAGE(bo, kt)                           \
    llds16(Ag + (kt), AsW + (bo));              \
    llds16(Ag + (kt) + 16 * ND, AsW + (bo) + 16 * BK); \
    llds16(Bg + (kt), BsW + (bo));              \
    llds16(Bg + (kt) + 16 * ND, BsW + (bo) + 16 * BK);

    f32x4 acc[4][4];
#pragma unroll
    for (int mi = 0; mi < 4; ++mi)
#pragma unroll
        for (int ni = 0; ni < 4; ++ni)
            acc[mi][ni] = (f32x4){0.f, 0.f, 0.f, 0.f};

    // prologue: stage tiles 0,1 into bufs 0,1 (8 loads outstanding)
    STAGE(0, 0)
    STAGE(ASZ, BK)

    int bc = 0;   // compute buffer index
    int bs = 2;   // stage buffer index (= bc+2 mod 3)
#pragma unroll 1
    for (int ki = 0; ki < NKI; ++ki) {
        if (ki + 1 < NKI) {
            asm volatile("s_waitcnt vmcnt(4)" ::: "memory");  // tile ki landed
        } else {
            asm volatile("s_waitcnt vmcnt(0)" ::: "memory");  // last tile landed
        }
        __builtin_amdgcn_s_barrier();          // all waves' tile-ki loads visible
        __builtin_amdgcn_sched_barrier(0);     // no ds_read hoisting above barrier

        if (ki + 2 < NKI) {
            const int bo = bs * ASZ;
            const int kt = (ki + 2) * BK;
            STAGE(bo, kt)
        }

        const int bco = bc * ASZ;
        bf16x8 af[4], bv[4];
#pragma unroll
        for (int mi = 0; mi < 4; ++mi)
            af[mi] = *reinterpret_cast<const bf16x8*>(A0 + bco + (wr * 64 + mi * 16 + fr) * BK + fk);
#pragma unroll
        for (int ni = 0; ni < 4; ++ni)
            bv[ni] = *reinterpret_cast<const bf16x8*>(B0 + bco + (wc * 64 + ni * 16 + fr) * BK + fk);
#pragma unroll
        for (int mi = 0; mi < 4; ++mi)
#pragma unroll
            for (int ni = 0; ni < 4; ++ni)
                acc[mi][ni] = __builtin_amdgcn_mfma_f32_16x16x32_bf16(af[mi], bv[ni],
                                                                      acc[mi][ni], 0, 0, 0);
        bc = (bc == 2) ? 0 : bc + 1;
        bs = (bs == 2) ? 0 : bs + 1;
    }
#undef STAGE

    // epilogue: D[row][col], col = lane&15, row = (lane>>4)*4 + r
    const size_t bbase = (size_t)b * ND * NL;
#pragma unroll
    for (int mi = 0; mi < 4; ++mi) {
#pragma unroll
        for (int r = 0; r < 4; ++r) {
            const int o = m0 + wr * 64 + mi * 16 + (lane >> 4) * 4 + r;
            const float bm = bmix[o];
            const size_t rowbase = bbase + (size_t)o * NL;
#pragma unroll
            for (int ni = 0; ni < 4; ++ni) {
                const int l = n0 + wc * 64 + ni * 16 + fr;
                mixed[rowbase + l] = f2bf(acc[mi][ni][r] + bm);
            }
        }
    }
}

// ------------------------- K4: z = mixed + x (regs) -> LayerNorm over channels -> out
__global__ __launch_bounds__(512) void ln_kernel(const unsigned short* __restrict__ mixed,
                                                 const float* __restrict__ x,
                                                 const float* __restrict__ gamma,
                                                 const float* __restrict__ beta,
                                                 float* __restrict__ out) {
    const int b = blockIdx.y;
    const int l0 = blockIdx.x * 32;
    const int tl = threadIdx.x & 31, tg = threadIdx.x >> 5;  // 16 c-groups x 32 cols
    const size_t base = (size_t)b * ND * NL + l0 + tl;

    float zv[64];
    float s = 0.f, q = 0.f;
#pragma unroll
    for (int j = 0; j < 64; ++j) {
        const size_t idx = base + (size_t)(tg + j * 16) * NL;
        const float v = bf2f(mixed[idx]) + x[idx];
        zv[j] = v;
        s += v;
        q += v * v;
    }

    __shared__ float sred[16][33], qred[16][33];
    __shared__ float mu_s[32], rs_s[32];
    sred[tg][tl] = s;
    qred[tg][tl] = q;
    __syncthreads();
    if (tg == 0) {
        float S = 0.f, Q = 0.f;
#pragma unroll
        for (int g = 0; g < 16; ++g) {
            S += sred[g][tl];
            Q += qred[g][tl];
        }
        const float mu = S * (1.f / ND);
        const float var = Q * (1.f / ND) - mu * mu;
        mu_s[tl] = mu;
        rs_s[tl] = rsqrtf(var + LN_EPS);
    }
    __syncthreads();
    const float mu = mu_s[tl], rs = rs_s[tl];
#pragma unroll
    for (int j = 0; j < 64; ++j) {
        const int c = tg + j * 16;
        out[base + (size_t)c * NL] = (zv[j] - mu) * rs * gamma[c] + beta[c];
    }
}

extern "C" void kernel_launch(void* const* d_in, const int* in_sizes, int n_in,
                              void* d_out, int out_size, void* d_ws, size_t ws_size,
                              hipStream_t stream) {
    (void)in_sizes; (void)n_in; (void)out_size; (void)ws_size;
    const float* x = (const float*)d_in[0];
    const float* h0 = (const float*)d_in[1];
    const float* h1 = (const float*)d_in[2];
    const float* wmix = (const float*)d_in[3];
    const float* bmix = (const float*)d_in[4];
    const float* gamma = (const float*)d_in[5];
    const float* beta = (const float*)d_in[6];
    float* out = (float*)d_out;

    char* ws = (char*)d_ws;
    unsigned short* ybf = (unsigned short*)(ws);                              // 16 MiB
    unsigned short* yT = (unsigned short*)(ws + (size_t)16 * 1024 * 1024);    // 16 MiB
    unsigned short* wbf = (unsigned short*)(ws + (size_t)32 * 1024 * 1024);   // 2 MiB
    unsigned short* mixed = (unsigned short*)(ws + (size_t)34 * 1024 * 1024); // 16 MiB

    wconv_kernel<<<dim3(ND * ND / (256 * 8)), 256, 0, stream>>>(wmix, wbf);
    conv_cascade_kernel<<<dim3(NB * ND), 512, 0, stream>>>(x, h0, h1, ybf);
    transpose_kernel<<<dim3(NL / 64, ND / 64, NB), 256, 0, stream>>>(ybf, yT);
    gemm_kernel<<<dim3(NL / BN, ND / BM, NB), 256, 0, stream>>>(wbf, yT, bmix, mixed);
    ln_kernel<<<dim3(NL / 32, NB), 512, 0, stream>>>(mixed, x, gamma, beta, out);
}